// Round 1
// baseline (311.757 us; speedup 1.0000x reference)
//
#include <hip/hip_runtime.h>
#include <cmath>

// Problem constants (fixed by reference)
#define NB   4      // batch
#define LQ   2048   // query len
#define SK   2048   // source len
#define DD   256    // in depth
#define HD   256    // hidden
#define FC   8      // heads
#define CH   32     // channels per head (HD/FC)
#define MHEAD 32    // NB*FC

// ------------------------------------------------------------------
// Generic f32 GEMM  C = A(MxK) @ B(KxN) + bias, 64x64 tile, 4x4/thread
// EPI 0: plain row-major to C0
// EPI 1: N=256, split heads -> C0[(n*8+f)*2048 + l][c]   (c = col%32)
// EPI 2: N=512, split heads -> point C0 / value C1, 64 cols per head
// ------------------------------------------------------------------
template<int EPI>
__global__ __launch_bounds__(256)
void gemm_bias_kernel(const float* __restrict__ A, const float* __restrict__ B,
                      const float* __restrict__ bias,
                      float* __restrict__ C0, float* __restrict__ C1,
                      int M, int N, int K)
{
    __shared__ float As[16][68];   // [k][m], +4 pad keeps 16B align, breaks conflicts
    __shared__ float Bs[16][64];   // [k][n]
    const int tx = threadIdx.x & 15;
    const int ty = threadIdx.x >> 4;
    const int bm = blockIdx.y * 64;
    const int bn = blockIdx.x * 64;
    float acc[4][4] = {};

    for (int k0 = 0; k0 < K; k0 += 16) {
        {
            const int row = threadIdx.x >> 2;            // 0..63
            const int kq  = (threadIdx.x & 3) << 2;      // 0,4,8,12
            const float4 a4 = *(const float4*)&A[(size_t)(bm + row) * K + k0 + kq];
            As[kq + 0][row] = a4.x;
            As[kq + 1][row] = a4.y;
            As[kq + 2][row] = a4.z;
            As[kq + 3][row] = a4.w;
            const int kr = threadIdx.x >> 4;             // 0..15
            const int nq = (threadIdx.x & 15) << 2;      // 0..60
            *(float4*)&Bs[kr][nq] = *(const float4*)&B[(size_t)(k0 + kr) * N + bn + nq];
        }
        __syncthreads();
        #pragma unroll
        for (int kk = 0; kk < 16; ++kk) {
            const float4 a4 = *(const float4*)&As[kk][ty << 2];
            const float4 b4 = *(const float4*)&Bs[kk][tx << 2];
            const float av[4] = {a4.x, a4.y, a4.z, a4.w};
            const float bv[4] = {b4.x, b4.y, b4.z, b4.w};
            #pragma unroll
            for (int i = 0; i < 4; ++i)
                #pragma unroll
                for (int j = 0; j < 4; ++j)
                    acc[i][j] = fmaf(av[i], bv[j], acc[i][j]);
        }
        __syncthreads();
    }

    #pragma unroll
    for (int i = 0; i < 4; ++i) {
        const int row = bm + (ty << 2) + i;
        #pragma unroll
        for (int j = 0; j < 4; ++j) {
            const int col = bn + (tx << 2) + j;
            const float v = acc[i][j] + bias[col];
            if (EPI == 0) {
                C0[(size_t)row * N + col] = v;
            } else if (EPI == 1) {
                const int n = row >> 11, l = row & 2047;
                const int f = col >> 5,  c = col & 31;
                C0[((((size_t)n * FC + f) * LQ) + l) * CH + c] = v;
            } else {
                const int n = row >> 11, s = row & 2047;
                const int f = col >> 6,  c64 = col & 63;
                float* dst = (c64 < CH) ? C0 : C1;
                dst[((((size_t)n * FC + f) * SK) + s) * CH + (c64 & 31)] = v;
            }
        }
    }
}

// ------------------------------------------------------------------
// L2 normalize rows of 32 (F.normalize semantics: x / max(||x||, eps))
// ------------------------------------------------------------------
__global__ __launch_bounds__(256)
void l2norm_kernel(float* __restrict__ x, int nrows)
{
    const int r = blockIdx.x * blockDim.x + threadIdx.x;
    if (r >= nrows) return;
    float* p = x + (size_t)r * CH;
    float4 v[8];
    float ss = 0.f;
    #pragma unroll
    for (int i = 0; i < 8; ++i) {
        v[i] = *(const float4*)(p + i * 4);
        ss = fmaf(v[i].x, v[i].x, ss);
        ss = fmaf(v[i].y, v[i].y, ss);
        ss = fmaf(v[i].z, v[i].z, ss);
        ss = fmaf(v[i].w, v[i].w, ss);
    }
    float nrm = fmaxf(sqrtf(ss), 1e-12f);
    #pragma unroll
    for (int i = 0; i < 8; ++i) {
        float4 w;
        w.x = v[i].x / nrm; w.y = v[i].y / nrm;
        w.z = v[i].z / nrm; w.w = v[i].w / nrm;
        *(float4*)(p + i * 4) = w;
    }
}

// ------------------------------------------------------------------
// sim = alpha*dot(qn, kn)+beta ; running max + first argmax.
// Grid: 32 heads * 8 qtiles * 2 s-halves = 512 blocks, 256 thr (1 query/thr)
// ------------------------------------------------------------------
__global__ __launch_bounds__(256)
void simmax_kernel(const float* __restrict__ q,   // (32,2048,32) normalized
                   const float* __restrict__ k,   // (32,2048,32) normalized
                   const float* __restrict__ alpha, const float* __restrict__ beta,
                   float* __restrict__ pval, int* __restrict__ pidx)
{
    __shared__ float ks[128 * CH];   // 16 KB tile
    const int b    = blockIdx.x;
    const int half = b & 1;
    const int qt   = (b >> 1) & 7;
    const int h    = b >> 4;
    const int l    = qt * 256 + threadIdx.x;

    const float* qrow = q + ((size_t)h * LQ + l) * CH;
    float qr[32];
    #pragma unroll
    for (int i = 0; i < 8; ++i) {
        const float4 v = *(const float4*)(qrow + i * 4);
        qr[i * 4 + 0] = v.x; qr[i * 4 + 1] = v.y;
        qr[i * 4 + 2] = v.z; qr[i * 4 + 3] = v.w;
    }
    const float a  = alpha[0];
    const float be = beta[0];

    float best = -INFINITY;
    int   bidx = 0;
    const int s_begin = half * (SK / 2);
    for (int s0 = s_begin; s0 < s_begin + SK / 2; s0 += 128) {
        const float4* src = (const float4*)(k + ((size_t)h * SK + s0) * CH);
        float4* dst = (float4*)ks;
        #pragma unroll
        for (int i = 0; i < 4; ++i)
            dst[threadIdx.x + i * 256] = src[threadIdx.x + i * 256];
        __syncthreads();
        for (int r = 0; r < 128; ++r) {
            const float* kr = ks + r * CH;
            float p0 = 0.f, p1 = 0.f, p2 = 0.f, p3 = 0.f;
            #pragma unroll
            for (int c4 = 0; c4 < 8; ++c4) {
                const float4 kv = *(const float4*)(kr + c4 * 4);
                p0 = fmaf(qr[c4 * 4 + 0], kv.x, p0);
                p1 = fmaf(qr[c4 * 4 + 1], kv.y, p1);
                p2 = fmaf(qr[c4 * 4 + 2], kv.z, p2);
                p3 = fmaf(qr[c4 * 4 + 3], kv.w, p3);
            }
            const float d  = (p0 + p1) + (p2 + p3);
            const float tv = fmaf(a, d, be);
            if (tv > best) { best = tv; bidx = s0 + r; }   // strict > keeps first max
        }
        __syncthreads();
    }
    const int out = h * LQ + l;
    pval[half * (MHEAD * LQ) + out] = best;
    pidx[half * (MHEAD * LQ) + out] = bidx;
}

// ------------------------------------------------------------------
// Merge the two s-halves, sigmoid, gather value row, scale, write
// new_x0 in (n, l, 256) layout.
// ------------------------------------------------------------------
__global__ __launch_bounds__(256)
void merge_gather_kernel(const float* __restrict__ pval, const int* __restrict__ pidx,
                         const float* __restrict__ xv,   // (32,2048,32) values
                         float* __restrict__ nx)         // (4,2048,256)
{
    const int r = blockIdx.x * blockDim.x + threadIdx.x;  // h*2048 + l
    const int h = r >> 11, l = r & 2047;
    const float v0 = pval[r],            v1 = pval[MHEAD * LQ + r];
    const int   i0 = pidx[r],            i1 = pidx[MHEAD * LQ + r];
    const bool  take0 = (v0 >= v1);                       // lower half wins ties
    const float t   = take0 ? v0 : v1;
    const int   idx = take0 ? i0 : i1;
    // numerically stable sigmoid
    float val;
    if (t >= 0.f) val = 1.f / (1.f + expf(-t));
    else          { const float e = expf(t); val = e / (1.f + e); }

    const float4* vr = (const float4*)(xv + ((size_t)h * SK + idx) * CH);
    const int n = h >> 3, f = h & 7;
    float4* out = (float4*)(nx + (((size_t)n * LQ + l) * (FC * CH)) + f * CH);
    #pragma unroll
    for (int i = 0; i < 8; ++i) {
        float4 w = vr[i];
        w.x *= val; w.y *= val; w.z *= val; w.w *= val;
        out[i] = w;
    }
}

// ------------------------------------------------------------------
extern "C" void kernel_launch(void* const* d_in, const int* in_sizes, int n_in,
                              void* d_out, int out_size, void* d_ws, size_t ws_size,
                              hipStream_t stream)
{
    const float* x0 = (const float*)d_in[0];
    const float* x1 = (const float*)d_in[1];
    const float* W0 = (const float*)d_in[2];
    const float* b0 = (const float*)d_in[3];
    const float* W1 = (const float*)d_in[4];
    const float* b1 = (const float*)d_in[5];
    const float* Wm = (const float*)d_in[6];
    const float* bm = (const float*)d_in[7];
    const float* alpha = (const float*)d_in[8];
    const float* beta  = (const float*)d_in[9];
    float* out = (float*)d_out;

    char* ws = (char*)d_ws;
    const size_t MB = 1024ull * 1024ull;
    float* x0q  = (float*)(ws + 0);        // (32,2048,32) 8MB
    float* x1k  = (float*)(ws + 8 * MB);   // (32,2048,32) 8MB
    float* x1v  = (float*)(ws + 16 * MB);  // (32,2048,32) 8MB
    float* nx   = (float*)(ws + 24 * MB);  // (4,2048,256) 8MB
    float* pval = (float*)(ws + 32 * MB);  // 2*65536 f32
    int*   pidx = (int*)  (ws + 32 * MB + 512 * 1024);

    const int Mrows = NB * LQ;   // 8192

    // K1: x0p = x0 @ W0 + b0  -> split-head layout
    gemm_bias_kernel<1><<<dim3(HD / 64, Mrows / 64), 256, 0, stream>>>(
        x0, W0, b0, x0q, nullptr, Mrows, HD, DD);
    // K2: x1p = x1 @ W1 + b1  -> point/value split-head layout
    gemm_bias_kernel<2><<<dim3(2 * HD / 64, Mrows / 64), 256, 0, stream>>>(
        x1, W1, b1, x1k, x1v, Mrows, 2 * HD, DD);
    // K3: L2 normalize q and k rows
    l2norm_kernel<<<(MHEAD * LQ) / 256, 256, 0, stream>>>(x0q, MHEAD * LQ);
    l2norm_kernel<<<(MHEAD * SK) / 256, 256, 0, stream>>>(x1k, MHEAD * SK);
    // K4: similarity max/argmax (s split in two halves)
    simmax_kernel<<<512, 256, 0, stream>>>(x0q, x1k, alpha, beta, pval, pidx);
    // K5: merge halves + sigmoid + gather + scale
    merge_gather_kernel<<<(MHEAD * LQ) / 256, 256, 0, stream>>>(pval, pidx, x1v, nx);
    // K6: out = nx @ Wm + bm
    gemm_bias_kernel<0><<<dim3(DD / 64, Mrows / 64), 256, 0, stream>>>(
        nx, Wm, bm, out, nullptr, Mrows, DD, DD);
}

// Round 2
// 221.400 us; speedup vs baseline: 1.4081x; 1.4081x over previous
//
#include <hip/hip_runtime.h>
#include <cmath>

// Problem constants (fixed by reference)
#define NB   4      // batch
#define LQ   2048   // query len
#define SK   2048   // source len
#define DD   256    // in depth
#define HD   256    // hidden
#define FC   8      // heads
#define CH   32     // channels per head (HD/FC)
#define MHEAD 32    // NB*FC

// ------------------------------------------------------------------
// Generic f32 GEMM  C = A(MxK) @ B(KxN) + bias, 64x64 tile, 4x4/thread
// EPI 0: plain row-major to C0
// EPI 1: N=256, split heads -> C0[(n*8+f)*2048 + l][c]   (c = col%32)
// EPI 2: N=512, split heads -> point C0 / value C1, 64 cols per head
// ------------------------------------------------------------------
template<int EPI>
__global__ __launch_bounds__(256)
void gemm_bias_kernel(const float* __restrict__ A, const float* __restrict__ B,
                      const float* __restrict__ bias,
                      float* __restrict__ C0, float* __restrict__ C1,
                      int M, int N, int K)
{
    __shared__ float As[16][68];
    __shared__ float Bs[16][64];
    const int tx = threadIdx.x & 15;
    const int ty = threadIdx.x >> 4;
    const int bm = blockIdx.y * 64;
    const int bn = blockIdx.x * 64;
    float acc[4][4] = {};

    for (int k0 = 0; k0 < K; k0 += 16) {
        {
            const int row = threadIdx.x >> 2;            // 0..63
            const int kq  = (threadIdx.x & 3) << 2;      // 0,4,8,12
            const float4 a4 = *(const float4*)&A[(size_t)(bm + row) * K + k0 + kq];
            As[kq + 0][row] = a4.x;
            As[kq + 1][row] = a4.y;
            As[kq + 2][row] = a4.z;
            As[kq + 3][row] = a4.w;
            const int kr = threadIdx.x >> 4;             // 0..15
            const int nq = (threadIdx.x & 15) << 2;      // 0..60
            *(float4*)&Bs[kr][nq] = *(const float4*)&B[(size_t)(k0 + kr) * N + bn + nq];
        }
        __syncthreads();
        #pragma unroll
        for (int kk = 0; kk < 16; ++kk) {
            const float4 a4 = *(const float4*)&As[kk][ty << 2];
            const float4 b4 = *(const float4*)&Bs[kk][tx << 2];
            const float av[4] = {a4.x, a4.y, a4.z, a4.w};
            const float bv[4] = {b4.x, b4.y, b4.z, b4.w};
            #pragma unroll
            for (int i = 0; i < 4; ++i)
                #pragma unroll
                for (int j = 0; j < 4; ++j)
                    acc[i][j] = fmaf(av[i], bv[j], acc[i][j]);
        }
        __syncthreads();
    }

    #pragma unroll
    for (int i = 0; i < 4; ++i) {
        const int row = bm + (ty << 2) + i;
        #pragma unroll
        for (int j = 0; j < 4; ++j) {
            const int col = bn + (tx << 2) + j;
            const float v = acc[i][j] + bias[col];
            if (EPI == 0) {
                C0[(size_t)row * N + col] = v;
            } else if (EPI == 1) {
                const int n = row >> 11, l = row & 2047;
                const int f = col >> 5,  c = col & 31;
                C0[((((size_t)n * FC + f) * LQ) + l) * CH + c] = v;
            } else {
                const int n = row >> 11, s = row & 2047;
                const int f = col >> 6,  c64 = col & 63;
                float* dst = (c64 < CH) ? C0 : C1;
                dst[((((size_t)n * FC + f) * SK) + s) * CH + (c64 & 31)] = v;
            }
        }
    }
}

// ------------------------------------------------------------------
// L2 normalize rows of 32 (F.normalize). If alpha != nullptr, also
// multiply by sign(alpha[0]) (folds alpha's sign out of the argmax).
// ------------------------------------------------------------------
__global__ __launch_bounds__(256)
void l2norm_kernel(float* __restrict__ x, int nrows, const float* __restrict__ alpha)
{
    const int r = blockIdx.x * blockDim.x + threadIdx.x;
    if (r >= nrows) return;
    float* p = x + (size_t)r * CH;
    float4 v[8];
    float ss = 0.f;
    #pragma unroll
    for (int i = 0; i < 8; ++i) {
        v[i] = *(const float4*)(p + i * 4);
        ss = fmaf(v[i].x, v[i].x, ss);
        ss = fmaf(v[i].y, v[i].y, ss);
        ss = fmaf(v[i].z, v[i].z, ss);
        ss = fmaf(v[i].w, v[i].w, ss);
    }
    float sgn = 1.f;
    if (alpha) sgn = (alpha[0] < 0.f) ? -1.f : 1.f;
    const float inv = sgn / fmaxf(sqrtf(ss), 1e-12f);
    #pragma unroll
    for (int i = 0; i < 8; ++i) {
        float4 w;
        w.x = v[i].x * inv; w.y = v[i].y * inv;
        w.z = v[i].z * inv; w.w = v[i].w * inv;
        *(float4*)(p + i * 4) = w;
    }
}

// ------------------------------------------------------------------
// simmax v2: 4 queries per thread in registers, software-pipelined
// k-row reads, packed (value,first-index) u64 atomicMax merge.
// Grid: 32 heads * 2 qtiles * 8 s-parts = 512 blocks, 256 threads.
// ------------------------------------------------------------------
__global__ __launch_bounds__(256, 2)
void simmax_kernel(const float* __restrict__ q,   // (32,2048,32) normalized*sgn
                   const float* __restrict__ k,   // (32,2048,32) normalized
                   unsigned long long* __restrict__ pmax)
{
    __shared__ float ks[128 * CH];   // 16 KB tile
    const int b    = blockIdx.x;
    const int part = b & 7;          // s part (256 rows each)
    const int qt   = (b >> 3) & 1;   // q tile (1024 queries each)
    const int h    = b >> 4;         // head
    const int t    = threadIdx.x;

    // 4 query rows per thread, strided by 256 for coalesced output
    float qr[4][32];
    #pragma unroll
    for (int i = 0; i < 4; ++i) {
        const float* qrow = q + ((size_t)h * LQ + qt * 1024 + i * 256 + t) * CH;
        #pragma unroll
        for (int c = 0; c < 8; ++c) {
            const float4 v = *(const float4*)(qrow + c * 4);
            qr[i][c * 4 + 0] = v.x; qr[i][c * 4 + 1] = v.y;
            qr[i][c * 4 + 2] = v.z; qr[i][c * 4 + 3] = v.w;
        }
    }

    float best0 = -INFINITY, best1 = -INFINITY, best2 = -INFINITY, best3 = -INFINITY;
    int   idx0 = 0, idx1 = 0, idx2 = 0, idx3 = 0;

    const int s_begin = part * 256;
    for (int s0 = s_begin; s0 < s_begin + 256; s0 += 128) {
        // stage 128 x 32 floats
        {
            const float4* src = (const float4*)(k + ((size_t)h * SK + s0) * CH);
            float4* dst = (float4*)ks;
            #pragma unroll
            for (int i = 0; i < 4; ++i)
                dst[t + i * 256] = src[t + i * 256];
        }
        __syncthreads();

        const float4* ksv = (const float4*)ks;
        float4 ka[8], kb[8];
        #pragma unroll
        for (int j = 0; j < 8; ++j) ka[j] = ksv[j];

        #define COMPUTE(KV, SIDX)                                            \
        {                                                                    \
            float p0 = 0.f, p1 = 0.f, p2 = 0.f, p3 = 0.f;                    \
            _Pragma("unroll")                                                \
            for (int c = 0; c < 8; ++c) {                                    \
                const float4 v = KV[c];                                      \
                p0 = fmaf(qr[0][c*4+0], v.x, p0);                            \
                p1 = fmaf(qr[1][c*4+0], v.x, p1);                            \
                p2 = fmaf(qr[2][c*4+0], v.x, p2);                            \
                p3 = fmaf(qr[3][c*4+0], v.x, p3);                            \
                p0 = fmaf(qr[0][c*4+1], v.y, p0);                            \
                p1 = fmaf(qr[1][c*4+1], v.y, p1);                            \
                p2 = fmaf(qr[2][c*4+1], v.y, p2);                            \
                p3 = fmaf(qr[3][c*4+1], v.y, p3);                            \
                p0 = fmaf(qr[0][c*4+2], v.z, p0);                            \
                p1 = fmaf(qr[1][c*4+2], v.z, p1);                            \
                p2 = fmaf(qr[2][c*4+2], v.z, p2);                            \
                p3 = fmaf(qr[3][c*4+2], v.z, p3);                            \
                p0 = fmaf(qr[0][c*4+3], v.w, p0);                            \
                p1 = fmaf(qr[1][c*4+3], v.w, p1);                            \
                p2 = fmaf(qr[2][c*4+3], v.w, p2);                            \
                p3 = fmaf(qr[3][c*4+3], v.w, p3);                            \
            }                                                                \
            if (p0 > best0) { best0 = p0; idx0 = (SIDX); }                   \
            if (p1 > best1) { best1 = p1; idx1 = (SIDX); }                   \
            if (p2 > best2) { best2 = p2; idx2 = (SIDX); }                   \
            if (p3 > best3) { best3 = p3; idx3 = (SIDX); }                   \
        }

        #pragma unroll 1
        for (int r = 0; r < 128; r += 2) {
            #pragma unroll
            for (int j = 0; j < 8; ++j) kb[j] = ksv[(r + 1) * 8 + j];
            COMPUTE(ka, s0 + r)
            if (r + 2 < 128) {
                #pragma unroll
                for (int j = 0; j < 8; ++j) ka[j] = ksv[(r + 2) * 8 + j];
            }
            COMPUTE(kb, s0 + r + 1)
        }
        #undef COMPUTE
        __syncthreads();
    }

    // encode (value, first-index) into u64: ordered-float key, smaller idx wins ties
    #define EMIT(BEST, IDX, I)                                               \
    {                                                                        \
        unsigned int u  = __float_as_uint(BEST);                             \
        unsigned int vk = (u & 0x80000000u) ? ~u : (u | 0x80000000u);        \
        unsigned long long key = ((unsigned long long)vk << 32)              \
                               | (unsigned int)(SK - 1 - (IDX));             \
        atomicMax(&pmax[(size_t)h * LQ + qt * 1024 + (I) * 256 + t], key);   \
    }
    EMIT(best0, idx0, 0)
    EMIT(best1, idx1, 1)
    EMIT(best2, idx2, 2)
    EMIT(best3, idx3, 3)
    #undef EMIT
}

// ------------------------------------------------------------------
// Decode packed max, sigmoid(|a|*d' + beta), gather value row, scale.
// ------------------------------------------------------------------
__global__ __launch_bounds__(256)
void gather_kernel(const unsigned long long* __restrict__ pmax,
                   const float* __restrict__ xv,   // (32,2048,32) values
                   const float* __restrict__ alpha, const float* __restrict__ beta,
                   float* __restrict__ nx)         // (4,2048,256)
{
    const int r = blockIdx.x * blockDim.x + threadIdx.x;  // h*2048 + l
    const int h = r >> 11, l = r & 2047;
    const unsigned long long key = pmax[r];
    const unsigned int vk = (unsigned int)(key >> 32);
    const unsigned int u  = (vk & 0x80000000u) ? (vk & 0x7fffffffu) : ~vk;
    const float dp = __uint_as_float(u);             // = sign(a) * dot
    int idx = SK - 1 - (int)(key & 0xffffffffu);
    const float a = alpha[0], be = beta[0];
    float tv;
    if (a == 0.f) { idx = 0; tv = be; }              // all sims equal -> argmax 0
    else          { tv = fmaf(fabsf(a), dp, be); }   // a*d = |a| * (sgn*d)
    float val;
    if (tv >= 0.f) val = 1.f / (1.f + expf(-tv));
    else           { const float e = expf(tv); val = e / (1.f + e); }

    const float4* vr = (const float4*)(xv + ((size_t)h * SK + idx) * CH);
    const int n = h >> 3, f = h & 7;
    float4* out = (float4*)(nx + (((size_t)n * LQ + l) * (FC * CH)) + f * CH);
    #pragma unroll
    for (int i = 0; i < 8; ++i) {
        float4 w = vr[i];
        w.x *= val; w.y *= val; w.z *= val; w.w *= val;
        out[i] = w;
    }
}

// ------------------------------------------------------------------
extern "C" void kernel_launch(void* const* d_in, const int* in_sizes, int n_in,
                              void* d_out, int out_size, void* d_ws, size_t ws_size,
                              hipStream_t stream)
{
    const float* x0 = (const float*)d_in[0];
    const float* x1 = (const float*)d_in[1];
    const float* W0 = (const float*)d_in[2];
    const float* b0 = (const float*)d_in[3];
    const float* W1 = (const float*)d_in[4];
    const float* b1 = (const float*)d_in[5];
    const float* Wm = (const float*)d_in[6];
    const float* bm = (const float*)d_in[7];
    const float* alpha = (const float*)d_in[8];
    const float* beta  = (const float*)d_in[9];
    float* out = (float*)d_out;

    char* ws = (char*)d_ws;
    const size_t MB = 1024ull * 1024ull;
    float* x0q  = (float*)(ws + 0);        // (32,2048,32) 8MB
    float* x1k  = (float*)(ws + 8 * MB);   // (32,2048,32) 8MB
    float* x1v  = (float*)(ws + 16 * MB);  // (32,2048,32) 8MB
    float* nx   = (float*)(ws + 24 * MB);  // (4,2048,256) 8MB
    unsigned long long* pmax = (unsigned long long*)(ws + 32 * MB); // 512KB

    const int Mrows = NB * LQ;   // 8192

    // init packed-max buffer (0 < any encoded value)
    hipMemsetAsync(pmax, 0, (size_t)MHEAD * LQ * 8, stream);

    // K1: x0p = x0 @ W0 + b0  -> split-head layout
    gemm_bias_kernel<1><<<dim3(HD / 64, Mrows / 64), 256, 0, stream>>>(
        x0, W0, b0, x0q, nullptr, Mrows, HD, DD);
    // K2: x1p = x1 @ W1 + b1  -> point/value split-head layout
    gemm_bias_kernel<2><<<dim3(2 * HD / 64, Mrows / 64), 256, 0, stream>>>(
        x1, W1, b1, x1k, x1v, Mrows, 2 * HD, DD);
    // K3: L2 normalize q (with sign(alpha) folded) and k rows
    l2norm_kernel<<<(MHEAD * LQ) / 256, 256, 0, stream>>>(x0q, MHEAD * LQ, alpha);
    l2norm_kernel<<<(MHEAD * SK) / 256, 256, 0, stream>>>(x1k, MHEAD * SK, nullptr);
    // K4: similarity max/argmax
    simmax_kernel<<<512, 256, 0, stream>>>(x0q, x1k, pmax);
    // K5: decode + sigmoid + gather + scale
    gather_kernel<<<(MHEAD * LQ) / 256, 256, 0, stream>>>(pmax, x1v, alpha, beta, nx);
    // K6: out = nx @ Wm + bm
    gemm_bias_kernel<0><<<dim3(DD / 64, Mrows / 64), 256, 0, stream>>>(
        nx, Wm, bm, out, nullptr, Mrows, DD, DD);
}

// Round 4
// 177.513 us; speedup vs baseline: 1.7563x; 1.2472x over previous
//
#include <hip/hip_runtime.h>
#include <hip/hip_bf16.h>
#include <cmath>

// Problem constants (fixed by reference)
#define NB   4      // batch
#define LQ   2048   // query len
#define SK   2048   // source len
#define DD   256    // in depth
#define HD   256    // hidden
#define FC   8      // heads
#define CH   32     // channels per head (HD/FC)
#define MHEAD 32    // NB*FC

// hh-filter margin: |f32dot - bf16dot| <= 2*2^-9*||q||*||k|| (~0.0040) per
// side, two sides + MFMA accum slack -> 0.0085.
#define MARGIN 0.0085f
#define CAP    12   // candidate slots per row (avg ~1.2 needed)

typedef float f32x16 __attribute__((ext_vector_type(16)));
typedef short bf16x8 __attribute__((ext_vector_type(8)));
typedef unsigned short ushort8v __attribute__((ext_vector_type(8)));

__device__ inline unsigned short f32_to_bf16_bits(float v) {
    __hip_bfloat16 b = __float2bfloat16(v);   // round-to-nearest
    return __builtin_bit_cast(unsigned short, b);
}

// ------------------------------------------------------------------
// Generic f32 GEMM  C = A(MxK) @ B(KxN) + bias, 64x64 tile, 4x4/thread
// (unchanged from the passing R2 kernel)
// ------------------------------------------------------------------
template<int EPI>
__global__ __launch_bounds__(256)
void gemm_bias_kernel(const float* __restrict__ A, const float* __restrict__ B,
                      const float* __restrict__ bias,
                      float* __restrict__ C0, float* __restrict__ C1,
                      int M, int N, int K)
{
    __shared__ float As[16][68];
    __shared__ float Bs[16][64];
    const int tx = threadIdx.x & 15;
    const int ty = threadIdx.x >> 4;
    const int bm = blockIdx.y * 64;
    const int bn = blockIdx.x * 64;
    float acc[4][4] = {};

    for (int k0 = 0; k0 < K; k0 += 16) {
        {
            const int row = threadIdx.x >> 2;
            const int kq  = (threadIdx.x & 3) << 2;
            const float4 a4 = *(const float4*)&A[(size_t)(bm + row) * K + k0 + kq];
            As[kq + 0][row] = a4.x;
            As[kq + 1][row] = a4.y;
            As[kq + 2][row] = a4.z;
            As[kq + 3][row] = a4.w;
            const int kr = threadIdx.x >> 4;
            const int nq = (threadIdx.x & 15) << 2;
            *(float4*)&Bs[kr][nq] = *(const float4*)&B[(size_t)(k0 + kr) * N + bn + nq];
        }
        __syncthreads();
        #pragma unroll
        for (int kk = 0; kk < 16; ++kk) {
            const float4 a4 = *(const float4*)&As[kk][ty << 2];
            const float4 b4 = *(const float4*)&Bs[kk][tx << 2];
            const float av[4] = {a4.x, a4.y, a4.z, a4.w};
            const float bv[4] = {b4.x, b4.y, b4.z, b4.w};
            #pragma unroll
            for (int i = 0; i < 4; ++i)
                #pragma unroll
                for (int j = 0; j < 4; ++j)
                    acc[i][j] = fmaf(av[i], bv[j], acc[i][j]);
        }
        __syncthreads();
    }

    #pragma unroll
    for (int i = 0; i < 4; ++i) {
        const int row = bm + (ty << 2) + i;
        #pragma unroll
        for (int j = 0; j < 4; ++j) {
            const int col = bn + (tx << 2) + j;
            const float v = acc[i][j] + bias[col];
            if (EPI == 0) {
                C0[(size_t)row * N + col] = v;
            } else if (EPI == 1) {
                const int n = row >> 11, l = row & 2047;
                const int f = col >> 5,  c = col & 31;
                C0[((((size_t)n * FC + f) * LQ) + l) * CH + c] = v;
            } else {
                const int n = row >> 11, s = row & 2047;
                const int f = col >> 6,  c64 = col & 63;
                float* dst = (c64 < CH) ? C0 : C1;
                dst[((((size_t)n * FC + f) * SK) + s) * CH + (c64 & 31)] = v;
            }
        }
    }
}

// ------------------------------------------------------------------
// L2-normalize rows of 32 IN PLACE (bit-identical to passing R2 l2norm),
// fold sign(alpha) (q only), and emit bf16(hi) copy for the MFMA filter.
// ------------------------------------------------------------------
__global__ __launch_bounds__(256)
void norm_hi_kernel(float* __restrict__ x, unsigned short* __restrict__ dhi,
                    int nrows, const float* __restrict__ alpha)
{
    const int r = blockIdx.x * blockDim.x + threadIdx.x;
    if (r >= nrows) return;
    float* p = x + (size_t)r * CH;
    float4 v[8];
    float ss = 0.f;
    #pragma unroll
    for (int i = 0; i < 8; ++i) {
        v[i] = *(const float4*)(p + i * 4);
        ss = fmaf(v[i].x, v[i].x, ss);
        ss = fmaf(v[i].y, v[i].y, ss);
        ss = fmaf(v[i].z, v[i].z, ss);
        ss = fmaf(v[i].w, v[i].w, ss);
    }
    float sgn = 1.f;
    if (alpha) sgn = (alpha[0] < 0.f) ? -1.f : 1.f;
    const float inv = sgn / fmaxf(sqrtf(ss), 1e-12f);

    ushort8v hb[4];
    #pragma unroll
    for (int i = 0; i < 8; ++i) {
        float4 w;
        w.x = v[i].x * inv; w.y = v[i].y * inv;
        w.z = v[i].z * inv; w.w = v[i].w * inv;
        *(float4*)(p + i * 4) = w;
        hb[i >> 1][(i & 1) * 4 + 0] = f32_to_bf16_bits(w.x);
        hb[i >> 1][(i & 1) * 4 + 1] = f32_to_bf16_bits(w.y);
        hb[i >> 1][(i & 1) * 4 + 2] = f32_to_bf16_bits(w.z);
        hb[i >> 1][(i & 1) * 4 + 3] = f32_to_bf16_bits(w.w);
    }
    #pragma unroll
    for (int i = 0; i < 4; ++i)
        *(ushort8v*)(dhi + (size_t)r * CH + i * 8) = hb[i];
}

// ------------------------------------------------------------------
// Pass A1: bf16 MFMA scan, per-row max of hh-similarity (no index).
// Grid: 32 heads * 16 qb(128 rows) = 512 blocks, 4 waves, 32 q/wave.
// ------------------------------------------------------------------
#define MFMA32(a, b, c) __builtin_amdgcn_mfma_f32_32x32x16_bf16(a, b, c, 0, 0, 0)

__global__ __launch_bounds__(256, 2)
void maxpass_kernel(const unsigned short* __restrict__ qhi,
                    const unsigned short* __restrict__ khi,
                    float* __restrict__ maxhh)
{
    const int b    = blockIdx.x;
    const int qb   = b & 15;
    const int h    = b >> 4;
    const int wave = threadIdx.x >> 6;
    const int lane = threadIdx.x & 63;
    const int qbase = qb * 128 + wave * 32;
    const int col   = lane & 31;
    const int g8    = (lane >> 5) * 8;

    const size_t qoff = ((size_t)h * LQ + qbase + col) * CH + g8;
    const bf16x8 ah0 = *(const bf16x8*)(qhi + qoff);
    const bf16x8 ah1 = *(const bf16x8*)(qhi + qoff + 16);

    const unsigned short* kh = khi + (size_t)h * SK * CH;
    const size_t koff = (size_t)col * CH + g8;

    float maxv[16];
    #pragma unroll
    for (int r = 0; r < 16; ++r) maxv[r] = -INFINITY;

    bf16x8 nb0 = *(const bf16x8*)(kh + koff);
    bf16x8 nb1 = *(const bf16x8*)(kh + koff + 16);

    for (int sb = 0; sb < SK / 32; ++sb) {
        const bf16x8 b0 = nb0, b1 = nb1;
        if (sb < SK / 32 - 1) {
            const size_t o2 = koff + (size_t)(sb + 1) * 32 * CH;
            nb0 = *(const bf16x8*)(kh + o2);
            nb1 = *(const bf16x8*)(kh + o2 + 16);
        }
        f32x16 c = {0.f, 0.f, 0.f, 0.f, 0.f, 0.f, 0.f, 0.f,
                    0.f, 0.f, 0.f, 0.f, 0.f, 0.f, 0.f, 0.f};
        c = MFMA32(ah0, b0, c);
        c = MFMA32(ah1, b1, c);
        #pragma unroll
        for (int r = 0; r < 16; ++r) maxv[r] = fmaxf(maxv[r], c[r]);
    }

    #pragma unroll
    for (int r = 0; r < 16; ++r) {
        float v = maxv[r];
        #pragma unroll
        for (int m = 16; m >= 1; m >>= 1)
            v = fmaxf(v, __shfl_xor(v, m, 64));
        maxv[r] = v;
    }
    if (col == 0) {
        const int rbase = h * LQ + qbase + 4 * (lane >> 5);
        #pragma unroll
        for (int r = 0; r < 16; ++r)
            maxhh[rbase + (r & 3) + 8 * (r >> 2)] = maxv[r];
    }
}

// ------------------------------------------------------------------
// Pass A2: identical MFMA scan; append s with hh >= maxhh[row]-MARGIN.
// ------------------------------------------------------------------
__global__ __launch_bounds__(256, 2)
void candpass_kernel(const unsigned short* __restrict__ qhi,
                     const unsigned short* __restrict__ khi,
                     const float* __restrict__ maxhh,
                     int* __restrict__ cnt, int* __restrict__ cand)
{
    const int b    = blockIdx.x;
    const int qb   = b & 15;
    const int h    = b >> 4;
    const int wave = threadIdx.x >> 6;
    const int lane = threadIdx.x & 63;
    const int qbase = qb * 128 + wave * 32;
    const int col   = lane & 31;
    const int g8    = (lane >> 5) * 8;

    const size_t qoff = ((size_t)h * LQ + qbase + col) * CH + g8;
    const bf16x8 ah0 = *(const bf16x8*)(qhi + qoff);
    const bf16x8 ah1 = *(const bf16x8*)(qhi + qoff + 16);

    int   rows[16];
    float thr[16];
    {
        const int rbase = h * LQ + qbase + 4 * (lane >> 5);
        #pragma unroll
        for (int r = 0; r < 16; ++r) {
            rows[r] = rbase + (r & 3) + 8 * (r >> 2);
            thr[r]  = maxhh[rows[r]] - MARGIN;
        }
    }

    const unsigned short* kh = khi + (size_t)h * SK * CH;
    const size_t koff = (size_t)col * CH + g8;

    bf16x8 nb0 = *(const bf16x8*)(kh + koff);
    bf16x8 nb1 = *(const bf16x8*)(kh + koff + 16);

    for (int sb = 0; sb < SK / 32; ++sb) {
        const bf16x8 b0 = nb0, b1 = nb1;
        if (sb < SK / 32 - 1) {
            const size_t o2 = koff + (size_t)(sb + 1) * 32 * CH;
            nb0 = *(const bf16x8*)(kh + o2);
            nb1 = *(const bf16x8*)(kh + o2 + 16);
        }
        f32x16 c = {0.f, 0.f, 0.f, 0.f, 0.f, 0.f, 0.f, 0.f,
                    0.f, 0.f, 0.f, 0.f, 0.f, 0.f, 0.f, 0.f};
        c = MFMA32(ah0, b0, c);
        c = MFMA32(ah1, b1, c);
        const int s = sb * 32 + col;
        #pragma unroll
        for (int r = 0; r < 16; ++r) {
            if (c[r] >= thr[r]) {
                const int slot = atomicAdd(&cnt[rows[r]], 1);
                if (slot < CAP) cand[(size_t)rows[r] * CAP + slot] = s;
            }
        }
    }
}

// ------------------------------------------------------------------
// Pass B: exact f32 refine over candidates (summation order bit-identical
// to the passing R2 kernel) + sigmoid + gather + scale + write new_x0.
// ------------------------------------------------------------------
__global__ __launch_bounds__(256)
void refine_gather_kernel(const float* __restrict__ qn,   // (32,2048,32) normalized*sgn
                          const float* __restrict__ kn,   // (32,2048,32) normalized
                          const int* __restrict__ cnt, const int* __restrict__ cand,
                          const float* __restrict__ xv,   // (32,2048,32) values
                          const float* __restrict__ alpha, const float* __restrict__ beta,
                          float* __restrict__ nx)         // (4,2048,256)
{
    const int r = blockIdx.x * blockDim.x + threadIdx.x;  // h*2048 + l
    const int h = r >> 11, l = r & 2047;

    float qr[CH];
    #pragma unroll
    for (int i = 0; i < 8; ++i) {
        const float4 v = *(const float4*)(qn + (size_t)r * CH + i * 4);
        qr[i * 4 + 0] = v.x; qr[i * 4 + 1] = v.y;
        qr[i * 4 + 2] = v.z; qr[i * 4 + 3] = v.w;
    }

    int m = cnt[r];
    if (m > CAP) m = CAP;
    float best = -INFINITY;
    int   bidx = 0x7fffffff;
    for (int j = 0; j < m; ++j) {
        const int s = cand[(size_t)r * CAP + j];
        const float4* k4 = (const float4*)(kn + ((size_t)h * SK + s) * CH);
        // sequential channel-order chain == R2's per-query dot
        float p = 0.f;
        #pragma unroll
        for (int c = 0; c < 8; ++c) {
            const float4 kv = k4[c];
            p = fmaf(qr[c * 4 + 0], kv.x, p);
            p = fmaf(qr[c * 4 + 1], kv.y, p);
            p = fmaf(qr[c * 4 + 2], kv.z, p);
            p = fmaf(qr[c * 4 + 3], kv.w, p);
        }
        if (p > best || (p == best && s < bidx)) { best = p; bidx = s; }
    }
    if (bidx == 0x7fffffff) bidx = 0;   // unreachable guard

    const float a = alpha[0], be = beta[0];
    float tv;
    int idx = bidx;
    if (a == 0.f) { idx = 0; tv = be; }           // all sims equal -> argmax 0
    else          { tv = fmaf(fabsf(a), best, be); }
    float val;
    if (tv >= 0.f) val = 1.f / (1.f + expf(-tv));
    else           { const float e = expf(tv); val = e / (1.f + e); }

    const float4* vr = (const float4*)(xv + ((size_t)h * SK + idx) * CH);
    const int n = h >> 3, f = h & 7;
    float4* out = (float4*)(nx + (((size_t)n * LQ + l) * (FC * CH)) + f * CH);
    #pragma unroll
    for (int i = 0; i < 8; ++i) {
        float4 w = vr[i];
        w.x *= val; w.y *= val; w.z *= val; w.w *= val;
        out[i] = w;
    }
}

// ------------------------------------------------------------------
extern "C" void kernel_launch(void* const* d_in, const int* in_sizes, int n_in,
                              void* d_out, int out_size, void* d_ws, size_t ws_size,
                              hipStream_t stream)
{
    const float* x0 = (const float*)d_in[0];
    const float* x1 = (const float*)d_in[1];
    const float* W0 = (const float*)d_in[2];
    const float* b0 = (const float*)d_in[3];
    const float* W1 = (const float*)d_in[4];
    const float* b1 = (const float*)d_in[5];
    const float* Wm = (const float*)d_in[6];
    const float* bm = (const float*)d_in[7];
    const float* alpha = (const float*)d_in[8];
    const float* beta  = (const float*)d_in[9];
    float* out = (float*)d_out;

    char* ws = (char*)d_ws;
    const size_t MB = 1024ull * 1024ull;
    float* x0q = (float*)(ws + 0);          // (32,2048,32) f32, normalized in place
    float* x1k = (float*)(ws + 8 * MB);     // (32,2048,32) f32, normalized in place
    float* x1v = (float*)(ws + 16 * MB);    // (32,2048,32) f32 values
    unsigned short* qhi = (unsigned short*)(ws + 24 * MB);  // 4MB
    unsigned short* khi = (unsigned short*)(ws + 28 * MB);  // 4MB
    float* maxhh = (float*)(ws + 32 * MB);                  // 256KB
    int*   cnt   = (int*)(ws + 32 * MB + 256 * 1024);       // 256KB
    int*   cand  = (int*)(ws + 32 * MB + 512 * 1024);       // 3MB (CAP=12)
    float* nx    = (float*)(ws + 24 * MB);  // reuse qhi/khi (dead after A2)

    const int Mrows = NB * LQ;   // 8192

    // K1: x0p = x0 @ W0 + b0  -> split-head layout
    gemm_bias_kernel<1><<<dim3(HD / 64, Mrows / 64), 256, 0, stream>>>(
        x0, W0, b0, x0q, nullptr, Mrows, HD, DD);
    // K2: x1p = x1 @ W1 + b1  -> point/value split-head layout
    gemm_bias_kernel<2><<<dim3(2 * HD / 64, Mrows / 64), 256, 0, stream>>>(
        x1, W1, b1, x1k, x1v, Mrows, 2 * HD, DD);
    // K3: normalize in place + bf16 hi copies
    norm_hi_kernel<<<(MHEAD * LQ) / 256, 256, 0, stream>>>(x0q, qhi, MHEAD * LQ, alpha);
    norm_hi_kernel<<<(MHEAD * SK) / 256, 256, 0, stream>>>(x1k, khi, MHEAD * SK, nullptr);
    // K4: zero candidate counters
    hipMemsetAsync(cnt, 0, (size_t)MHEAD * LQ * sizeof(int), stream);
    // K5: MFMA hh max per row
    maxpass_kernel<<<512, 256, 0, stream>>>(qhi, khi, maxhh);
    // K6: MFMA hh candidate collection
    candpass_kernel<<<512, 256, 0, stream>>>(qhi, khi, maxhh, cnt, cand);
    // K7: exact refine + sigmoid + gather + scale
    refine_gather_kernel<<<(MHEAD * LQ) / 256, 256, 0, stream>>>(
        x0q, x1k, cnt, cand, x1v, alpha, beta, nx);
    // K8: out = nx @ Wm + bm
    gemm_bias_kernel<0><<<dim3(DD / 64, Mrows / 64), 256, 0, stream>>>(
        nx, Wm, bm, out, nullptr, Mrows, DD, DD);
}

// Round 5
// 157.732 us; speedup vs baseline: 1.9765x; 1.1254x over previous
//
#include <hip/hip_runtime.h>
#include <hip/hip_bf16.h>
#include <cmath>

// Problem constants (fixed by reference)
#define NB   4      // batch
#define LQ   2048   // query len
#define SK   2048   // source len
#define DD   256    // in depth
#define HD   256    // hidden
#define FC   8      // heads
#define CH   32     // channels per head (HD/FC)
#define MHEAD 32    // NB*FC

// hh-filter margin: |f32dot - bf16dot| <= 2*2^-9 per side (unit rows) + slack
#define MARGIN 0.0085f
#define CAP    12   // candidate slots per row (avg ~1.2 needed)

typedef float f32x16 __attribute__((ext_vector_type(16)));
typedef short bf16x8 __attribute__((ext_vector_type(8)));
typedef unsigned short ushort8v __attribute__((ext_vector_type(8)));

__device__ inline unsigned short f32_to_bf16_bits(float v) {
    __hip_bfloat16 b = __float2bfloat16(v);   // round-to-nearest
    return __builtin_bit_cast(unsigned short, b);
}
__device__ inline unsigned int ord_encode(float v) {
    unsigned int u = __float_as_uint(v);
    return (u & 0x80000000u) ? ~u : (u | 0x80000000u);
}
__device__ inline float ord_decode(unsigned int e) {
    unsigned int u = (e & 0x80000000u) ? (e & 0x7fffffffu) : ~e;
    return __uint_as_float(u);
}

#define MFMA32(a, b, c) __builtin_amdgcn_mfma_f32_32x32x16_bf16(a, b, c, 0, 0, 0)

// ------------------------------------------------------------------
// Generic f32 GEMM  C = A(MxK) @ B(KxN) + bias, 64x64 tile, 4x4/thread
// (unchanged from the passing R2/R4 kernel — argmax path must stay f32)
// ------------------------------------------------------------------
template<int EPI>
__global__ __launch_bounds__(256)
void gemm_bias_kernel(const float* __restrict__ A, const float* __restrict__ B,
                      const float* __restrict__ bias,
                      float* __restrict__ C0, float* __restrict__ C1,
                      int M, int N, int K)
{
    __shared__ float As[16][68];
    __shared__ float Bs[16][64];
    const int tx = threadIdx.x & 15;
    const int ty = threadIdx.x >> 4;
    const int bm = blockIdx.y * 64;
    const int bn = blockIdx.x * 64;
    float acc[4][4] = {};

    for (int k0 = 0; k0 < K; k0 += 16) {
        {
            const int row = threadIdx.x >> 2;
            const int kq  = (threadIdx.x & 3) << 2;
            const float4 a4 = *(const float4*)&A[(size_t)(bm + row) * K + k0 + kq];
            As[kq + 0][row] = a4.x;
            As[kq + 1][row] = a4.y;
            As[kq + 2][row] = a4.z;
            As[kq + 3][row] = a4.w;
            const int kr = threadIdx.x >> 4;
            const int nq = (threadIdx.x & 15) << 2;
            *(float4*)&Bs[kr][nq] = *(const float4*)&B[(size_t)(k0 + kr) * N + bn + nq];
        }
        __syncthreads();
        #pragma unroll
        for (int kk = 0; kk < 16; ++kk) {
            const float4 a4 = *(const float4*)&As[kk][ty << 2];
            const float4 b4 = *(const float4*)&Bs[kk][tx << 2];
            const float av[4] = {a4.x, a4.y, a4.z, a4.w};
            const float bv[4] = {b4.x, b4.y, b4.z, b4.w};
            #pragma unroll
            for (int i = 0; i < 4; ++i)
                #pragma unroll
                for (int j = 0; j < 4; ++j)
                    acc[i][j] = fmaf(av[i], bv[j], acc[i][j]);
        }
        __syncthreads();
    }

    #pragma unroll
    for (int i = 0; i < 4; ++i) {
        const int row = bm + (ty << 2) + i;
        #pragma unroll
        for (int j = 0; j < 4; ++j) {
            const int col = bn + (tx << 2) + j;
            const float v = acc[i][j] + bias[col];
            if (EPI == 0) {
                C0[(size_t)row * N + col] = v;
            } else if (EPI == 1) {
                const int n = row >> 11, l = row & 2047;
                const int f = col >> 5,  c = col & 31;
                C0[((((size_t)n * FC + f) * LQ) + l) * CH + c] = v;
            } else {
                const int n = row >> 11, s = row & 2047;
                const int f = col >> 6,  c64 = col & 63;
                float* dst = (c64 < CH) ? C0 : C1;
                dst[((((size_t)n * FC + f) * SK) + s) * CH + (c64 & 31)] = v;
            }
        }
    }
}

// ------------------------------------------------------------------
// L2-normalize rows of 32 IN PLACE (bit-identical to R2), fold
// sign(alpha) (q only), emit bf16(hi) copy for the MFMA filter.
// ------------------------------------------------------------------
__global__ __launch_bounds__(256)
void norm_hi_kernel(float* __restrict__ x, unsigned short* __restrict__ dhi,
                    int nrows, const float* __restrict__ alpha)
{
    const int r = blockIdx.x * blockDim.x + threadIdx.x;
    if (r >= nrows) return;
    float* p = x + (size_t)r * CH;
    float4 v[8];
    float ss = 0.f;
    #pragma unroll
    for (int i = 0; i < 8; ++i) {
        v[i] = *(const float4*)(p + i * 4);
        ss = fmaf(v[i].x, v[i].x, ss);
        ss = fmaf(v[i].y, v[i].y, ss);
        ss = fmaf(v[i].z, v[i].z, ss);
        ss = fmaf(v[i].w, v[i].w, ss);
    }
    float sgn = 1.f;
    if (alpha) sgn = (alpha[0] < 0.f) ? -1.f : 1.f;
    const float inv = sgn / fmaxf(sqrtf(ss), 1e-12f);

    ushort8v hb[4];
    #pragma unroll
    for (int i = 0; i < 8; ++i) {
        float4 w;
        w.x = v[i].x * inv; w.y = v[i].y * inv;
        w.z = v[i].z * inv; w.w = v[i].w * inv;
        *(float4*)(p + i * 4) = w;
        hb[i >> 1][(i & 1) * 4 + 0] = f32_to_bf16_bits(w.x);
        hb[i >> 1][(i & 1) * 4 + 1] = f32_to_bf16_bits(w.y);
        hb[i >> 1][(i & 1) * 4 + 2] = f32_to_bf16_bits(w.z);
        hb[i >> 1][(i & 1) * 4 + 3] = f32_to_bf16_bits(w.w);
    }
    #pragma unroll
    for (int i = 0; i < 4; ++i)
        *(ushort8v*)(dhi + (size_t)r * CH + i * 8) = hb[i];
}

// ------------------------------------------------------------------
// Pass A1: bf16 MFMA scan, per-row hh max via ordered-uint atomicMax.
// Grid: 32 heads * 16 qb * 4 s-chunks = 2048 blocks, 4 waves.
// Depth-2 tile prefetch (4 tiles in flight).
// ------------------------------------------------------------------
__global__ __launch_bounds__(256, 4)
void maxpass_kernel(const unsigned short* __restrict__ qhi,
                    const unsigned short* __restrict__ khi,
                    unsigned int* __restrict__ maxhh_u)
{
    const int b    = blockIdx.x;
    const int sc   = b & 3;
    const int qb   = (b >> 2) & 15;
    const int h    = b >> 6;
    const int wave = threadIdx.x >> 6;
    const int lane = threadIdx.x & 63;
    const int qbase = qb * 128 + wave * 32;
    const int col   = lane & 31;
    const int g8    = (lane >> 5) * 8;

    const size_t qoff = ((size_t)h * LQ + qbase + col) * CH + g8;
    const bf16x8 ah0 = *(const bf16x8*)(qhi + qoff);
    const bf16x8 ah1 = *(const bf16x8*)(qhi + qoff + 16);

    const unsigned short* kh = khi + ((size_t)h * SK + sc * 512) * CH;
    const size_t koff = (size_t)col * CH + g8;

    float maxv[16];
    #pragma unroll
    for (int r = 0; r < 16; ++r) maxv[r] = -INFINITY;

    bf16x8 t0a = *(const bf16x8*)(kh + koff);
    bf16x8 t0b = *(const bf16x8*)(kh + koff + 16);
    bf16x8 t1a = *(const bf16x8*)(kh + koff + 32 * CH);
    bf16x8 t1b = *(const bf16x8*)(kh + koff + 32 * CH + 16);

    for (int sb = 0; sb < 16; sb += 2) {
        const bf16x8 c0a = t0a, c0b = t0b, c1a = t1a, c1b = t1b;
        if (sb + 2 < 16) {
            const size_t o = koff + (size_t)(sb + 2) * 32 * CH;
            t0a = *(const bf16x8*)(kh + o);
            t0b = *(const bf16x8*)(kh + o + 16);
            t1a = *(const bf16x8*)(kh + o + 32 * CH);
            t1b = *(const bf16x8*)(kh + o + 32 * CH + 16);
        }
        f32x16 c = {0.f, 0.f, 0.f, 0.f, 0.f, 0.f, 0.f, 0.f,
                    0.f, 0.f, 0.f, 0.f, 0.f, 0.f, 0.f, 0.f};
        c = MFMA32(ah0, c0a, c);
        c = MFMA32(ah1, c0b, c);
        #pragma unroll
        for (int r = 0; r < 16; ++r) maxv[r] = fmaxf(maxv[r], c[r]);
        f32x16 d = {0.f, 0.f, 0.f, 0.f, 0.f, 0.f, 0.f, 0.f,
                    0.f, 0.f, 0.f, 0.f, 0.f, 0.f, 0.f, 0.f};
        d = MFMA32(ah0, c1a, d);
        d = MFMA32(ah1, c1b, d);
        #pragma unroll
        for (int r = 0; r < 16; ++r) maxv[r] = fmaxf(maxv[r], d[r]);
    }

    #pragma unroll
    for (int r = 0; r < 16; ++r) {
        float v = maxv[r];
        #pragma unroll
        for (int m = 16; m >= 1; m >>= 1)
            v = fmaxf(v, __shfl_xor(v, m, 64));
        maxv[r] = v;
    }
    if (col == 0) {
        const int rbase = h * LQ + qbase + 4 * (lane >> 5);
        #pragma unroll
        for (int r = 0; r < 16; ++r)
            atomicMax(&maxhh_u[rbase + (r & 3) + 8 * (r >> 2)], ord_encode(maxv[r]));
    }
}

// ------------------------------------------------------------------
// Pass A2: identical MFMA scan; append s with hh >= max-MARGIN.
// Same 2048-block grid + depth-2 prefetch.
// ------------------------------------------------------------------
__global__ __launch_bounds__(256, 4)
void candpass_kernel(const unsigned short* __restrict__ qhi,
                     const unsigned short* __restrict__ khi,
                     const unsigned int* __restrict__ maxhh_u,
                     int* __restrict__ cnt, int* __restrict__ cand)
{
    const int b    = blockIdx.x;
    const int sc   = b & 3;
    const int qb   = (b >> 2) & 15;
    const int h    = b >> 6;
    const int wave = threadIdx.x >> 6;
    const int lane = threadIdx.x & 63;
    const int qbase = qb * 128 + wave * 32;
    const int col   = lane & 31;
    const int g8    = (lane >> 5) * 8;

    const size_t qoff = ((size_t)h * LQ + qbase + col) * CH + g8;
    const bf16x8 ah0 = *(const bf16x8*)(qhi + qoff);
    const bf16x8 ah1 = *(const bf16x8*)(qhi + qoff + 16);

    int   rows[16];
    float thr[16];
    {
        const int rbase = h * LQ + qbase + 4 * (lane >> 5);
        #pragma unroll
        for (int r = 0; r < 16; ++r) {
            rows[r] = rbase + (r & 3) + 8 * (r >> 2);
            thr[r]  = ord_decode(maxhh_u[rows[r]]) - MARGIN;
        }
    }

    const unsigned short* kh = khi + ((size_t)h * SK + sc * 512) * CH;
    const size_t koff = (size_t)col * CH + g8;
    const int sbase = sc * 512;

    bf16x8 t0a = *(const bf16x8*)(kh + koff);
    bf16x8 t0b = *(const bf16x8*)(kh + koff + 16);
    bf16x8 t1a = *(const bf16x8*)(kh + koff + 32 * CH);
    bf16x8 t1b = *(const bf16x8*)(kh + koff + 32 * CH + 16);

    for (int sb = 0; sb < 16; sb += 2) {
        const bf16x8 c0a = t0a, c0b = t0b, c1a = t1a, c1b = t1b;
        if (sb + 2 < 16) {
            const size_t o = koff + (size_t)(sb + 2) * 32 * CH;
            t0a = *(const bf16x8*)(kh + o);
            t0b = *(const bf16x8*)(kh + o + 16);
            t1a = *(const bf16x8*)(kh + o + 32 * CH);
            t1b = *(const bf16x8*)(kh + o + 32 * CH + 16);
        }
        f32x16 c = {0.f, 0.f, 0.f, 0.f, 0.f, 0.f, 0.f, 0.f,
                    0.f, 0.f, 0.f, 0.f, 0.f, 0.f, 0.f, 0.f};
        c = MFMA32(ah0, c0a, c);
        c = MFMA32(ah1, c0b, c);
        f32x16 d = {0.f, 0.f, 0.f, 0.f, 0.f, 0.f, 0.f, 0.f,
                    0.f, 0.f, 0.f, 0.f, 0.f, 0.f, 0.f, 0.f};
        d = MFMA32(ah0, c1a, d);
        d = MFMA32(ah1, c1b, d);
        const int s0 = sbase + sb * 32 + col;
        #pragma unroll
        for (int r = 0; r < 16; ++r) {
            if (c[r] >= thr[r]) {
                const int slot = atomicAdd(&cnt[rows[r]], 1);
                if (slot < CAP) cand[(size_t)rows[r] * CAP + slot] = s0;
            }
            if (d[r] >= thr[r]) {
                const int slot = atomicAdd(&cnt[rows[r]], 1);
                if (slot < CAP) cand[(size_t)rows[r] * CAP + slot] = s0 + 32;
            }
        }
    }
}

// ------------------------------------------------------------------
// Pass B: exact f32 refine (chain bit-identical to R2) + sigmoid +
// gather + scale; writes new_x0 as bf16 for the MFMA output GEMM.
// ------------------------------------------------------------------
__global__ __launch_bounds__(256)
void refine_gather_kernel(const float* __restrict__ qn,
                          const float* __restrict__ kn,
                          const int* __restrict__ cnt, const int* __restrict__ cand,
                          const float* __restrict__ xv,
                          const float* __restrict__ alpha, const float* __restrict__ beta,
                          unsigned short* __restrict__ nxb)  // (4,2048,256) bf16
{
    const int r = blockIdx.x * blockDim.x + threadIdx.x;  // h*2048 + l
    const int h = r >> 11, l = r & 2047;

    float qr[CH];
    #pragma unroll
    for (int i = 0; i < 8; ++i) {
        const float4 v = *(const float4*)(qn + (size_t)r * CH + i * 4);
        qr[i * 4 + 0] = v.x; qr[i * 4 + 1] = v.y;
        qr[i * 4 + 2] = v.z; qr[i * 4 + 3] = v.w;
    }

    int m = cnt[r];
    if (m > CAP) m = CAP;
    float best = -INFINITY;
    int   bidx = 0x7fffffff;
    for (int j = 0; j < m; ++j) {
        const int s = cand[(size_t)r * CAP + j];
        const float4* k4 = (const float4*)(kn + ((size_t)h * SK + s) * CH);
        float p = 0.f;
        #pragma unroll
        for (int c = 0; c < 8; ++c) {
            const float4 kv = k4[c];
            p = fmaf(qr[c * 4 + 0], kv.x, p);
            p = fmaf(qr[c * 4 + 1], kv.y, p);
            p = fmaf(qr[c * 4 + 2], kv.z, p);
            p = fmaf(qr[c * 4 + 3], kv.w, p);
        }
        if (p > best || (p == best && s < bidx)) { best = p; bidx = s; }
    }
    if (bidx == 0x7fffffff) bidx = 0;   // unreachable guard

    const float a = alpha[0], be = beta[0];
    float tv;
    int idx = bidx;
    if (a == 0.f) { idx = 0; tv = be; }
    else          { tv = fmaf(fabsf(a), best, be); }
    float val;
    if (tv >= 0.f) val = 1.f / (1.f + expf(-tv));
    else           { const float e = expf(tv); val = e / (1.f + e); }

    const float4* vr = (const float4*)(xv + ((size_t)h * SK + idx) * CH);
    const int n = h >> 3, f = h & 7;
    unsigned short* out = nxb + (((size_t)n * LQ + l) * (FC * CH)) + f * CH;
    #pragma unroll
    for (int i = 0; i < 8; ++i) {
        const float4 w = vr[i];
        ushort8v o;  // pack 2 float4 -> 8 bf16? (process per-4)
        o[0] = f32_to_bf16_bits(w.x * val);
        o[1] = f32_to_bf16_bits(w.y * val);
        o[2] = f32_to_bf16_bits(w.z * val);
        o[3] = f32_to_bf16_bits(w.w * val);
        // store 4 bf16 (8 bytes)
        *(unsigned long long*)(out + i * 4) = __builtin_bit_cast(unsigned long long,
            *(const ulong1*)&o);
    }
}

// ------------------------------------------------------------------
// Wm (256x256 f32, row-major [k][n]) -> bf16 swizzled B-frag layout:
// wm_s[(k>>4)*4096 + n*16 + (k&15)]
// ------------------------------------------------------------------
__global__ __launch_bounds__(256)
void wmprep_kernel(const float* __restrict__ Wm, unsigned short* __restrict__ wm_s)
{
    const int i = blockIdx.x * 256 + threadIdx.x;   // 0..65535
    const int k = i >> 8, n = i & 255;
    wm_s[(k >> 4) * 4096 + n * 16 + (k & 15)] = f32_to_bf16_bits(Wm[k * 256 + n]);
}

// ------------------------------------------------------------------
// K6: out = nx(bf16) @ Wm(bf16 swizzled) + bm, f32 out. MFMA 32x32 tiles.
// Grid: 512 blocks * 4 waves = 2048 tiles (256 m-tiles x 8 n-tiles).
// ------------------------------------------------------------------
__global__ __launch_bounds__(256)
void gemm_out_mfma_kernel(const unsigned short* __restrict__ nxb,
                          const unsigned short* __restrict__ wm_s,
                          const float* __restrict__ bm, float* __restrict__ out)
{
    const int wave = threadIdx.x >> 6;
    const int lane = threadIdx.x & 63;
    const int idx  = blockIdx.x * 4 + wave;
    const int mt   = idx >> 3;
    const int nt   = idx & 7;
    const int col  = lane & 31;
    const int g8   = (lane >> 5) * 8;

    const unsigned short* aptr = nxb + (size_t)(mt * 32 + col) * 256 + g8;
    const unsigned short* bptr = wm_s + nt * 32 * 16 + col * 16 + g8;

    f32x16 acc = {0.f, 0.f, 0.f, 0.f, 0.f, 0.f, 0.f, 0.f,
                  0.f, 0.f, 0.f, 0.f, 0.f, 0.f, 0.f, 0.f};
    #pragma unroll 4
    for (int kc = 0; kc < 16; ++kc) {
        const bf16x8 a = *(const bf16x8*)(aptr + kc * 16);
        const bf16x8 bfr = *(const bf16x8*)(bptr + (size_t)kc * 4096);
        acc = MFMA32(a, bfr, acc);
    }

    const int n0 = nt * 32;
    const float bias = bm[n0 + col];
    #pragma unroll
    for (int r = 0; r < 16; ++r) {
        const int row = mt * 32 + (r & 3) + 8 * (r >> 2) + 4 * (lane >> 5);
        out[(size_t)row * 256 + n0 + col] = acc[r] + bias;
    }
}

// ------------------------------------------------------------------
extern "C" void kernel_launch(void* const* d_in, const int* in_sizes, int n_in,
                              void* d_out, int out_size, void* d_ws, size_t ws_size,
                              hipStream_t stream)
{
    const float* x0 = (const float*)d_in[0];
    const float* x1 = (const float*)d_in[1];
    const float* W0 = (const float*)d_in[2];
    const float* b0 = (const float*)d_in[3];
    const float* W1 = (const float*)d_in[4];
    const float* b1 = (const float*)d_in[5];
    const float* Wm = (const float*)d_in[6];
    const float* bm = (const float*)d_in[7];
    const float* alpha = (const float*)d_in[8];
    const float* beta  = (const float*)d_in[9];
    float* out = (float*)d_out;

    char* ws = (char*)d_ws;
    const size_t MB = 1024ull * 1024ull;
    float* x0q = (float*)(ws + 0);          // (32,2048,32) f32, normalized in place
    float* x1k = (float*)(ws + 8 * MB);     // (32,2048,32) f32, normalized in place
    float* x1v = (float*)(ws + 16 * MB);    // (32,2048,32) f32 values
    unsigned short* qhi = (unsigned short*)(ws + 24 * MB);  // 4MB (dead after A2)
    unsigned short* khi = (unsigned short*)(ws + 28 * MB);  // 4MB
    unsigned int* maxhh_u = (unsigned int*)(ws + 32 * MB);            // 256KB
    int* cnt  = (int*)(ws + 32 * MB + 256 * 1024);                    // 256KB
    int* cand = (int*)(ws + 32 * MB + 512 * 1024);                    // 3MB
    unsigned short* wm_s = (unsigned short*)(ws + 32 * MB + 3584 * 1024); // 128KB
    unsigned short* nxb  = (unsigned short*)(ws + 24 * MB); // reuse qhi region

    const int Mrows = NB * LQ;   // 8192

    // K1: x0p = x0 @ W0 + b0  -> split-head layout (f32, argmax path)
    gemm_bias_kernel<1><<<dim3(HD / 64, Mrows / 64), 256, 0, stream>>>(
        x0, W0, b0, x0q, nullptr, Mrows, HD, DD);
    // K2: x1p = x1 @ W1 + b1  -> point/value split-head layout (f32)
    gemm_bias_kernel<2><<<dim3(2 * HD / 64, Mrows / 64), 256, 0, stream>>>(
        x1, W1, b1, x1k, x1v, Mrows, 2 * HD, DD);
    // Wm bf16 swizzle (independent)
    wmprep_kernel<<<256, 256, 0, stream>>>(Wm, wm_s);
    // K3: normalize in place + bf16 hi copies
    norm_hi_kernel<<<(MHEAD * LQ) / 256, 256, 0, stream>>>(x0q, qhi, MHEAD * LQ, alpha);
    norm_hi_kernel<<<(MHEAD * SK) / 256, 256, 0, stream>>>(x1k, khi, MHEAD * SK, nullptr);
    // zero counters / max buffers
    hipMemsetAsync(maxhh_u, 0, (size_t)MHEAD * LQ * 4, stream);
    hipMemsetAsync(cnt, 0, (size_t)MHEAD * LQ * 4, stream);
    // A1: MFMA hh max per row (s-split x4, atomicMax merge)
    maxpass_kernel<<<2048, 256, 0, stream>>>(qhi, khi, maxhh_u);
    // A2: MFMA hh candidate collection (s-split x4)
    candpass_kernel<<<2048, 256, 0, stream>>>(qhi, khi, maxhh_u, cnt, cand);
    // B: exact refine + sigmoid + gather + scale -> bf16 nx
    refine_gather_kernel<<<(MHEAD * LQ) / 256, 256, 0, stream>>>(
        x0q, x1k, cnt, cand, x1v, alpha, beta, nxb);
    // K6: out = nx @ Wm + bm via bf16 MFMA
    gemm_out_mfma_kernel<<<512, 256, 0, stream>>>(nxb, wm_s, bm, out);
}

// Round 6
// 149.922 us; speedup vs baseline: 2.0795x; 1.0521x over previous
//
#include <hip/hip_runtime.h>
#include <hip/hip_bf16.h>
#include <cmath>

// Problem constants (fixed by reference)
#define NB   4      // batch
#define LQ   2048   // query len
#define SK   2048   // source len
#define DD   256    // in depth
#define HD   256    // hidden
#define FC   8      // heads
#define CH   32     // channels per head (HD/FC)
#define MHEAD 32    // NB*FC

// hh-filter margin: |f32dot - bf16dot| <= 2*2^-9 per side (unit rows) + slack
#define MARGIN 0.0085f
#define CAP    12   // candidate slots per row (avg ~1.2 needed)

typedef float f32x16 __attribute__((ext_vector_type(16)));
typedef short bf16x8 __attribute__((ext_vector_type(8)));
typedef unsigned short ushort8v __attribute__((ext_vector_type(8)));

__device__ inline unsigned short f32_to_bf16_bits(float v) {
    __hip_bfloat16 b = __float2bfloat16(v);   // round-to-nearest
    return __builtin_bit_cast(unsigned short, b);
}
__device__ inline unsigned int ord_encode(float v) {
    unsigned int u = __float_as_uint(v);
    return (u & 0x80000000u) ? ~u : (u | 0x80000000u);
}
__device__ inline float ord_decode(unsigned int e) {
    unsigned int u = (e & 0x80000000u) ? (e & 0x7fffffffu) : ~e;
    return __uint_as_float(u);
}

#define MFMA32(a, b, c) __builtin_amdgcn_mfma_f32_32x32x16_bf16(a, b, c, 0, 0, 0)

// ------------------------------------------------------------------
// f32 GEMM  C = A(MxK) @ B(KxN) + bias, 64x64 tile, 4x4/thread,
// double-buffered LDS. FMA order per acc element identical to R2
// (argmax path must stay bit-stable).
// EPI 0: plain row-major; EPI 1: q split-head; EPI 2: point/value split.
// ------------------------------------------------------------------
template<int EPI>
__global__ __launch_bounds__(256)
void gemm_bias_kernel(const float* __restrict__ A, const float* __restrict__ B,
                      const float* __restrict__ bias,
                      float* __restrict__ C0, float* __restrict__ C1,
                      int M, int N, int K)
{
    __shared__ float As[2][16][68];
    __shared__ float Bs[2][16][64];
    const int tx = threadIdx.x & 15;
    const int ty = threadIdx.x >> 4;
    const int bm = blockIdx.y * 64;
    const int bn = blockIdx.x * 64;
    float acc[4][4] = {};

    const int arow = threadIdx.x >> 2;           // 0..63
    const int akq  = (threadIdx.x & 3) << 2;     // 0,4,8,12
    const int bkr  = threadIdx.x >> 4;           // 0..15
    const int bnq  = (threadIdx.x & 15) << 2;    // 0..60

    // prologue: stage chunk 0
    {
        const float4 a4 = *(const float4*)&A[(size_t)(bm + arow) * K + akq];
        const float4 b4 = *(const float4*)&B[(size_t)bkr * N + bn + bnq];
        As[0][akq + 0][arow] = a4.x;
        As[0][akq + 1][arow] = a4.y;
        As[0][akq + 2][arow] = a4.z;
        As[0][akq + 3][arow] = a4.w;
        *(float4*)&Bs[0][bkr][bnq] = b4;
    }
    __syncthreads();

    const int nchunk = K >> 4;
    float4 pa, pb;
    for (int c = 0; c < nchunk; ++c) {
        const int cur = c & 1;
        if (c + 1 < nchunk) {
            const int k0 = (c + 1) << 4;
            pa = *(const float4*)&A[(size_t)(bm + arow) * K + k0 + akq];
            pb = *(const float4*)&B[(size_t)(k0 + bkr) * N + bn + bnq];
        }
        #pragma unroll
        for (int kk = 0; kk < 16; ++kk) {
            const float4 a4 = *(const float4*)&As[cur][kk][ty << 2];
            const float4 b4 = *(const float4*)&Bs[cur][kk][tx << 2];
            const float av[4] = {a4.x, a4.y, a4.z, a4.w};
            const float bv[4] = {b4.x, b4.y, b4.z, b4.w};
            #pragma unroll
            for (int i = 0; i < 4; ++i)
                #pragma unroll
                for (int j = 0; j < 4; ++j)
                    acc[i][j] = fmaf(av[i], bv[j], acc[i][j]);
        }
        if (c + 1 < nchunk) {
            const int nxt = cur ^ 1;
            As[nxt][akq + 0][arow] = pa.x;
            As[nxt][akq + 1][arow] = pa.y;
            As[nxt][akq + 2][arow] = pa.z;
            As[nxt][akq + 3][arow] = pa.w;
            *(float4*)&Bs[nxt][bkr][bnq] = pb;
        }
        __syncthreads();
    }

    #pragma unroll
    for (int i = 0; i < 4; ++i) {
        const int row = bm + (ty << 2) + i;
        #pragma unroll
        for (int j = 0; j < 4; ++j) {
            const int col = bn + (tx << 2) + j;
            const float v = acc[i][j] + bias[col];
            if (EPI == 0) {
                C0[(size_t)row * N + col] = v;
            } else if (EPI == 1) {
                const int n = row >> 11, l = row & 2047;
                const int f = col >> 5,  c = col & 31;
                C0[((((size_t)n * FC + f) * LQ) + l) * CH + c] = v;
            } else {
                const int n = row >> 11, s = row & 2047;
                const int f = col >> 6,  c64 = col & 63;
                float* dst = (c64 < CH) ? C0 : C1;
                dst[((((size_t)n * FC + f) * SK) + s) * CH + (c64 & 31)] = v;
            }
        }
    }
}

// ------------------------------------------------------------------
// Combined: L2-normalize q rows (sign(alpha) folded) AND k rows, in
// place (arithmetic bit-identical to R2), emit bf16 hi copies, and
// zero-init maxhh_u/cnt (one entry per q row — replaces in-graph
// memsets, which profiled at ~43us each as fillBufferAligned).
// Grid: 512 blocks x 256 thr; r<65536 -> q row, else k row.
// ------------------------------------------------------------------
__global__ __launch_bounds__(256)
void norm_split_init_kernel(float* __restrict__ xq, unsigned short* __restrict__ qhi,
                            float* __restrict__ xk, unsigned short* __restrict__ khi,
                            const float* __restrict__ alpha,
                            unsigned int* __restrict__ maxhh_u, int* __restrict__ cnt)
{
    int r = blockIdx.x * blockDim.x + threadIdx.x;
    float* p;
    unsigned short* dhi;
    float sgn = 1.f;
    if (r < MHEAD * LQ) {
        maxhh_u[r] = 0u;      // ord_encode lower bound (0 < any encoded float)
        cnt[r] = 0;
        p   = xq + (size_t)r * CH;
        dhi = qhi + (size_t)r * CH;
        if (alpha[0] < 0.f) sgn = -1.f;
    } else {
        r -= MHEAD * LQ;
        p   = xk + (size_t)r * CH;
        dhi = khi + (size_t)r * CH;
    }

    float4 v[8];
    float ss = 0.f;
    #pragma unroll
    for (int i = 0; i < 8; ++i) {
        v[i] = *(const float4*)(p + i * 4);
        ss = fmaf(v[i].x, v[i].x, ss);
        ss = fmaf(v[i].y, v[i].y, ss);
        ss = fmaf(v[i].z, v[i].z, ss);
        ss = fmaf(v[i].w, v[i].w, ss);
    }
    const float inv = sgn / fmaxf(sqrtf(ss), 1e-12f);

    ushort8v hb[4];
    #pragma unroll
    for (int i = 0; i < 8; ++i) {
        float4 w;
        w.x = v[i].x * inv; w.y = v[i].y * inv;
        w.z = v[i].z * inv; w.w = v[i].w * inv;
        *(float4*)(p + i * 4) = w;
        hb[i >> 1][(i & 1) * 4 + 0] = f32_to_bf16_bits(w.x);
        hb[i >> 1][(i & 1) * 4 + 1] = f32_to_bf16_bits(w.y);
        hb[i >> 1][(i & 1) * 4 + 2] = f32_to_bf16_bits(w.z);
        hb[i >> 1][(i & 1) * 4 + 3] = f32_to_bf16_bits(w.w);
    }
    #pragma unroll
    for (int i = 0; i < 4; ++i)
        *(ushort8v*)(dhi + i * 8) = hb[i];
}

// ------------------------------------------------------------------
// Pass A1: bf16 MFMA scan, per-row hh max via ordered-uint atomicMax.
// Grid: 32 heads * 16 qb * 4 s-chunks = 2048 blocks, 4 waves.
// ------------------------------------------------------------------
__global__ __launch_bounds__(256, 4)
void maxpass_kernel(const unsigned short* __restrict__ qhi,
                    const unsigned short* __restrict__ khi,
                    unsigned int* __restrict__ maxhh_u)
{
    const int b    = blockIdx.x;
    const int sc   = b & 3;
    const int qb   = (b >> 2) & 15;
    const int h    = b >> 6;
    const int wave = threadIdx.x >> 6;
    const int lane = threadIdx.x & 63;
    const int qbase = qb * 128 + wave * 32;
    const int col   = lane & 31;
    const int g8    = (lane >> 5) * 8;

    const size_t qoff = ((size_t)h * LQ + qbase + col) * CH + g8;
    const bf16x8 ah0 = *(const bf16x8*)(qhi + qoff);
    const bf16x8 ah1 = *(const bf16x8*)(qhi + qoff + 16);

    const unsigned short* kh = khi + ((size_t)h * SK + sc * 512) * CH;
    const size_t koff = (size_t)col * CH + g8;

    float maxv[16];
    #pragma unroll
    for (int r = 0; r < 16; ++r) maxv[r] = -INFINITY;

    bf16x8 t0a = *(const bf16x8*)(kh + koff);
    bf16x8 t0b = *(const bf16x8*)(kh + koff + 16);
    bf16x8 t1a = *(const bf16x8*)(kh + koff + 32 * CH);
    bf16x8 t1b = *(const bf16x8*)(kh + koff + 32 * CH + 16);

    for (int sb = 0; sb < 16; sb += 2) {
        const bf16x8 c0a = t0a, c0b = t0b, c1a = t1a, c1b = t1b;
        if (sb + 2 < 16) {
            const size_t o = koff + (size_t)(sb + 2) * 32 * CH;
            t0a = *(const bf16x8*)(kh + o);
            t0b = *(const bf16x8*)(kh + o + 16);
            t1a = *(const bf16x8*)(kh + o + 32 * CH);
            t1b = *(const bf16x8*)(kh + o + 32 * CH + 16);
        }
        f32x16 c = {0.f, 0.f, 0.f, 0.f, 0.f, 0.f, 0.f, 0.f,
                    0.f, 0.f, 0.f, 0.f, 0.f, 0.f, 0.f, 0.f};
        c = MFMA32(ah0, c0a, c);
        c = MFMA32(ah1, c0b, c);
        #pragma unroll
        for (int r = 0; r < 16; ++r) maxv[r] = fmaxf(maxv[r], c[r]);
        f32x16 d = {0.f, 0.f, 0.f, 0.f, 0.f, 0.f, 0.f, 0.f,
                    0.f, 0.f, 0.f, 0.f, 0.f, 0.f, 0.f, 0.f};
        d = MFMA32(ah0, c1a, d);
        d = MFMA32(ah1, c1b, d);
        #pragma unroll
        for (int r = 0; r < 16; ++r) maxv[r] = fmaxf(maxv[r], d[r]);
    }

    #pragma unroll
    for (int r = 0; r < 16; ++r) {
        float v = maxv[r];
        #pragma unroll
        for (int m = 16; m >= 1; m >>= 1)
            v = fmaxf(v, __shfl_xor(v, m, 64));
        maxv[r] = v;
    }
    if (col == 0) {
        const int rbase = h * LQ + qbase + 4 * (lane >> 5);
        #pragma unroll
        for (int r = 0; r < 16; ++r)
            atomicMax(&maxhh_u[rbase + (r & 3) + 8 * (r >> 2)], ord_encode(maxv[r]));
    }
}

// ------------------------------------------------------------------
// Pass A2: identical MFMA scan; append s with hh >= max-MARGIN.
// ------------------------------------------------------------------
__global__ __launch_bounds__(256, 4)
void candpass_kernel(const unsigned short* __restrict__ qhi,
                     const unsigned short* __restrict__ khi,
                     const unsigned int* __restrict__ maxhh_u,
                     int* __restrict__ cnt, int* __restrict__ cand)
{
    const int b    = blockIdx.x;
    const int sc   = b & 3;
    const int qb   = (b >> 2) & 15;
    const int h    = b >> 6;
    const int wave = threadIdx.x >> 6;
    const int lane = threadIdx.x & 63;
    const int qbase = qb * 128 + wave * 32;
    const int col   = lane & 31;
    const int g8    = (lane >> 5) * 8;

    const size_t qoff = ((size_t)h * LQ + qbase + col) * CH + g8;
    const bf16x8 ah0 = *(const bf16x8*)(qhi + qoff);
    const bf16x8 ah1 = *(const bf16x8*)(qhi + qoff + 16);

    int   rows[16];
    float thr[16];
    {
        const int rbase = h * LQ + qbase + 4 * (lane >> 5);
        #pragma unroll
        for (int r = 0; r < 16; ++r) {
            rows[r] = rbase + (r & 3) + 8 * (r >> 2);
            thr[r]  = ord_decode(maxhh_u[rows[r]]) - MARGIN;
        }
    }

    const unsigned short* kh = khi + ((size_t)h * SK + sc * 512) * CH;
    const size_t koff = (size_t)col * CH + g8;
    const int sbase = sc * 512;

    bf16x8 t0a = *(const bf16x8*)(kh + koff);
    bf16x8 t0b = *(const bf16x8*)(kh + koff + 16);
    bf16x8 t1a = *(const bf16x8*)(kh + koff + 32 * CH);
    bf16x8 t1b = *(const bf16x8*)(kh + koff + 32 * CH + 16);

    for (int sb = 0; sb < 16; sb += 2) {
        const bf16x8 c0a = t0a, c0b = t0b, c1a = t1a, c1b = t1b;
        if (sb + 2 < 16) {
            const size_t o = koff + (size_t)(sb + 2) * 32 * CH;
            t0a = *(const bf16x8*)(kh + o);
            t0b = *(const bf16x8*)(kh + o + 16);
            t1a = *(const bf16x8*)(kh + o + 32 * CH);
            t1b = *(const bf16x8*)(kh + o + 32 * CH + 16);
        }
        f32x16 c = {0.f, 0.f, 0.f, 0.f, 0.f, 0.f, 0.f, 0.f,
                    0.f, 0.f, 0.f, 0.f, 0.f, 0.f, 0.f, 0.f};
        c = MFMA32(ah0, c0a, c);
        c = MFMA32(ah1, c0b, c);
        f32x16 d = {0.f, 0.f, 0.f, 0.f, 0.f, 0.f, 0.f, 0.f,
                    0.f, 0.f, 0.f, 0.f, 0.f, 0.f, 0.f, 0.f};
        d = MFMA32(ah0, c1a, d);
        d = MFMA32(ah1, c1b, d);
        const int s0 = sbase + sb * 32 + col;
        #pragma unroll
        for (int r = 0; r < 16; ++r) {
            if (c[r] >= thr[r]) {
                const int slot = atomicAdd(&cnt[rows[r]], 1);
                if (slot < CAP) cand[(size_t)rows[r] * CAP + slot] = s0;
            }
            if (d[r] >= thr[r]) {
                const int slot = atomicAdd(&cnt[rows[r]], 1);
                if (slot < CAP) cand[(size_t)rows[r] * CAP + slot] = s0 + 32;
            }
        }
    }
}

// ------------------------------------------------------------------
// Pass B: exact f32 refine (chain bit-identical to R2) + sigmoid +
// gather + scale; writes new_x0 as bf16 for the MFMA output GEMM.
// ------------------------------------------------------------------
__global__ __launch_bounds__(256)
void refine_gather_kernel(const float* __restrict__ qn,
                          const float* __restrict__ kn,
                          const int* __restrict__ cnt, const int* __restrict__ cand,
                          const float* __restrict__ xv,
                          const float* __restrict__ alpha, const float* __restrict__ beta,
                          unsigned short* __restrict__ nxb)  // (4,2048,256) bf16
{
    const int r = blockIdx.x * blockDim.x + threadIdx.x;  // h*2048 + l
    const int h = r >> 11, l = r & 2047;

    float qr[CH];
    #pragma unroll
    for (int i = 0; i < 8; ++i) {
        const float4 v = *(const float4*)(qn + (size_t)r * CH + i * 4);
        qr[i * 4 + 0] = v.x; qr[i * 4 + 1] = v.y;
        qr[i * 4 + 2] = v.z; qr[i * 4 + 3] = v.w;
    }

    int m = cnt[r];
    if (m > CAP) m = CAP;
    float best = -INFINITY;
    int   bidx = 0x7fffffff;
    for (int j = 0; j < m; ++j) {
        const int s = cand[(size_t)r * CAP + j];
        const float4* k4 = (const float4*)(kn + ((size_t)h * SK + s) * CH);
        float p = 0.f;
        #pragma unroll
        for (int c = 0; c < 8; ++c) {
            const float4 kv = k4[c];
            p = fmaf(qr[c * 4 + 0], kv.x, p);
            p = fmaf(qr[c * 4 + 1], kv.y, p);
            p = fmaf(qr[c * 4 + 2], kv.z, p);
            p = fmaf(qr[c * 4 + 3], kv.w, p);
        }
        if (p > best || (p == best && s < bidx)) { best = p; bidx = s; }
    }
    if (bidx == 0x7fffffff) bidx = 0;   // unreachable guard

    const float a = alpha[0], be = beta[0];
    float tv;
    int idx = bidx;
    if (a == 0.f) { idx = 0; tv = be; }
    else          { tv = fmaf(fabsf(a), best, be); }
    float val;
    if (tv >= 0.f) val = 1.f / (1.f + expf(-tv));
    else           { const float e = expf(tv); val = e / (1.f + e); }

    const float4* vr = (const float4*)(xv + ((size_t)h * SK + idx) * CH);
    const int n = h >> 3, f = h & 7;
    unsigned short* out = nxb + (((size_t)n * LQ + l) * (FC * CH)) + f * CH;
    #pragma unroll
    for (int i = 0; i < 8; ++i) {
        const float4 w = vr[i];
        ushort8v o;
        o[0] = f32_to_bf16_bits(w.x * val);
        o[1] = f32_to_bf16_bits(w.y * val);
        o[2] = f32_to_bf16_bits(w.z * val);
        o[3] = f32_to_bf16_bits(w.w * val);
        *(unsigned long long*)(out + i * 4) = __builtin_bit_cast(unsigned long long,
            *(const ulong1*)&o);
    }
}

// ------------------------------------------------------------------
// Wm (256x256 f32, row-major [k][n]) -> bf16 swizzled B-frag layout:
// wm_s[(k>>4)*4096 + n*16 + (k&15)]
// ------------------------------------------------------------------
__global__ __launch_bounds__(256)
void wmprep_kernel(const float* __restrict__ Wm, unsigned short* __restrict__ wm_s)
{
    const int i = blockIdx.x * 256 + threadIdx.x;   // 0..65535
    const int k = i >> 8, n = i & 255;
    wm_s[(k >> 4) * 4096 + n * 16 + (k & 15)] = f32_to_bf16_bits(Wm[k * 256 + n]);
}

// ------------------------------------------------------------------
// K6: out = nx(bf16) @ Wm(bf16 swizzled) + bm, f32 out. MFMA 32x32 tiles.
// ------------------------------------------------------------------
__global__ __launch_bounds__(256)
void gemm_out_mfma_kernel(const unsigned short* __restrict__ nxb,
                          const unsigned short* __restrict__ wm_s,
                          const float* __restrict__ bm, float* __restrict__ out)
{
    const int wave = threadIdx.x >> 6;
    const int lane = threadIdx.x & 63;
    const int idx  = blockIdx.x * 4 + wave;
    const int mt   = idx >> 3;
    const int nt   = idx & 7;
    const int col  = lane & 31;
    const int g8   = (lane >> 5) * 8;

    const unsigned short* aptr = nxb + (size_t)(mt * 32 + col) * 256 + g8;
    const unsigned short* bptr = wm_s + nt * 32 * 16 + col * 16 + g8;

    f32x16 acc = {0.f, 0.f, 0.f, 0.f, 0.f, 0.f, 0.f, 0.f,
                  0.f, 0.f, 0.f, 0.f, 0.f, 0.f, 0.f, 0.f};
    #pragma unroll 4
    for (int kc = 0; kc < 16; ++kc) {
        const bf16x8 a = *(const bf16x8*)(aptr + kc * 16);
        const bf16x8 bfr = *(const bf16x8*)(bptr + (size_t)kc * 4096);
        acc = MFMA32(a, bfr, acc);
    }

    const int n0 = nt * 32;
    const float bias = bm[n0 + col];
    #pragma unroll
    for (int r = 0; r < 16; ++r) {
        const int row = mt * 32 + (r & 3) + 8 * (r >> 2) + 4 * (lane >> 5);
        out[(size_t)row * 256 + n0 + col] = acc[r] + bias;
    }
}

// ------------------------------------------------------------------
extern "C" void kernel_launch(void* const* d_in, const int* in_sizes, int n_in,
                              void* d_out, int out_size, void* d_ws, size_t ws_size,
                              hipStream_t stream)
{
    const float* x0 = (const float*)d_in[0];
    const float* x1 = (const float*)d_in[1];
    const float* W0 = (const float*)d_in[2];
    const float* b0 = (const float*)d_in[3];
    const float* W1 = (const float*)d_in[4];
    const float* b1 = (const float*)d_in[5];
    const float* Wm = (const float*)d_in[6];
    const float* bm = (const float*)d_in[7];
    const float* alpha = (const float*)d_in[8];
    const float* beta  = (const float*)d_in[9];
    float* out = (float*)d_out;

    char* ws = (char*)d_ws;
    const size_t MB = 1024ull * 1024ull;
    float* x0q = (float*)(ws + 0);          // (32,2048,32) f32, normalized in place
    float* x1k = (float*)(ws + 8 * MB);     // (32,2048,32) f32, normalized in place
    float* x1v = (float*)(ws + 16 * MB);    // (32,2048,32) f32 values
    unsigned short* qhi = (unsigned short*)(ws + 24 * MB);  // 4MB (dead after A2)
    unsigned short* khi = (unsigned short*)(ws + 28 * MB);  // 4MB
    unsigned int* maxhh_u = (unsigned int*)(ws + 32 * MB);            // 256KB
    int* cnt  = (int*)(ws + 32 * MB + 256 * 1024);                    // 256KB
    int* cand = (int*)(ws + 32 * MB + 512 * 1024);                    // 3MB
    unsigned short* wm_s = (unsigned short*)(ws + 32 * MB + 3584 * 1024); // 128KB
    unsigned short* nxb  = (unsigned short*)(ws + 24 * MB); // reuse qhi region

    const int Mrows = NB * LQ;   // 8192

    // K1: x0p = x0 @ W0 + b0  -> split-head layout (f32, argmax path)
    gemm_bias_kernel<1><<<dim3(HD / 64, Mrows / 64), 256, 0, stream>>>(
        x0, W0, b0, x0q, nullptr, Mrows, HD, DD);
    // K2: x1p = x1 @ W1 + b1  -> point/value split-head layout (f32)
    gemm_bias_kernel<2><<<dim3(2 * HD / 64, Mrows / 64), 256, 0, stream>>>(
        x1, W1, b1, x1k, x1v, Mrows, 2 * HD, DD);
    // Wm bf16 swizzle (independent)
    wmprep_kernel<<<256, 256, 0, stream>>>(Wm, wm_s);
    // K3: normalize q+k in place + bf16 hi copies + zero-init maxhh/cnt
    norm_split_init_kernel<<<(2 * MHEAD * LQ) / 256, 256, 0, stream>>>(
        x0q, qhi, x1k, khi, alpha, maxhh_u, cnt);
    // A1: MFMA hh max per row (s-split x4, atomicMax merge)
    maxpass_kernel<<<2048, 256, 0, stream>>>(qhi, khi, maxhh_u);
    // A2: MFMA hh candidate collection (s-split x4)
    candpass_kernel<<<2048, 256, 0, stream>>>(qhi, khi, maxhh_u, cnt, cand);
    // B: exact refine + sigmoid + gather + scale -> bf16 nx
    refine_gather_kernel<<<(MHEAD * LQ) / 256, 256, 0, stream>>>(
        x0q, x1k, cnt, cand, x1v, alpha, beta, nxb);
    // K6: out = nx @ Wm + bm via bf16 MFMA
    gemm_out_mfma_kernel<<<512, 256, 0, stream>>>(nxb, wm_s, bm, out);
}

// Round 7
// 143.263 us; speedup vs baseline: 2.1761x; 1.0465x over previous
//
#include <hip/hip_runtime.h>
#include <hip/hip_bf16.h>
#include <cmath>

// Problem constants (fixed by reference)
#define NB   4      // batch
#define LQ   2048   // query len
#define SK   2048   // source len
#define DD   256    // in depth
#define HD   256    // hidden
#define FC   8      // heads
#define CH   32     // channels per head (HD/FC)
#define MHEAD 32    // NB*FC

// hh-filter margin: |f32dot - bf16dot| <= 2*2^-9 per side (unit rows) + slack
#define MARGIN 0.0085f
#define CAP    12   // candidate slots per row (avg ~1.2 needed)

typedef float f32x16 __attribute__((ext_vector_type(16)));
typedef float f32x2  __attribute__((ext_vector_type(2)));
typedef short bf16x8 __attribute__((ext_vector_type(8)));
typedef unsigned short ushort8v __attribute__((ext_vector_type(8)));

__device__ inline unsigned short f32_to_bf16_bits(float v) {
    __hip_bfloat16 b = __float2bfloat16(v);   // round-to-nearest
    return __builtin_bit_cast(unsigned short, b);
}
__device__ inline unsigned int ord_encode(float v) {
    unsigned int u = __float_as_uint(v);
    return (u & 0x80000000u) ? ~u : (u | 0x80000000u);
}
__device__ inline float ord_decode(unsigned int e) {
    unsigned int u = (e & 0x80000000u) ? (e & 0x7fffffffu) : ~e;
    return __uint_as_float(u);
}

#define MFMA32(a, b, c) __builtin_amdgcn_mfma_f32_32x32x16_bf16(a, b, c, 0, 0, 0)

// ------------------------------------------------------------------
// Merged projection GEMM (replaces K1+K2).
// Grid: dim3(12, 128). nt 0..3 -> x0@W0+b0 (EPI1 layout); nt 4..11 ->
// x1@W1+b1 (EPI2 point/value split). 64x64 tile, 4x4/thread, LDS dbuf,
// v_pk_fma_f32 inner loop. Per-acc-element FMA chain order identical
// to the passing R2/R6 kernel (argmax path must stay bit-stable).
// ------------------------------------------------------------------
__global__ __launch_bounds__(256)
void proj_gemm_kernel(const float* __restrict__ x0, const float* __restrict__ x1,
                      const float* __restrict__ W0, const float* __restrict__ b0f,
                      const float* __restrict__ W1, const float* __restrict__ b1f,
                      float* __restrict__ xq, float* __restrict__ xk,
                      float* __restrict__ xv)
{
    __shared__ float As[2][16][68];
    __shared__ float Bs[2][16][64];
    const int nt  = blockIdx.x;            // 0..11 (wave-uniform branch)
    const bool is0 = (nt < 4);
    const float* A    = is0 ? x0 : x1;
    const float* B    = is0 ? W0 : W1;
    const float* bias = is0 ? b0f : b1f;
    const int N  = is0 ? HD : 2 * HD;
    const int bn = (is0 ? nt : nt - 4) * 64;
    const int bm = blockIdx.y * 64;
    const int K  = DD;

    const int tx = threadIdx.x & 15;
    const int ty = threadIdx.x >> 4;
    f32x2 acc2[4][2] = {};

    const int arow = threadIdx.x >> 2;           // 0..63
    const int akq  = (threadIdx.x & 3) << 2;     // 0,4,8,12
    const int bkr  = threadIdx.x >> 4;           // 0..15
    const int bnq  = (threadIdx.x & 15) << 2;    // 0..60

    // prologue: stage chunk 0
    {
        const float4 a4 = *(const float4*)&A[(size_t)(bm + arow) * K + akq];
        const float4 b4 = *(const float4*)&B[(size_t)bkr * N + bn + bnq];
        As[0][akq + 0][arow] = a4.x;
        As[0][akq + 1][arow] = a4.y;
        As[0][akq + 2][arow] = a4.z;
        As[0][akq + 3][arow] = a4.w;
        *(float4*)&Bs[0][bkr][bnq] = b4;
    }
    __syncthreads();

    const int nchunk = K >> 4;   // 16
    float4 pa, pb;
    for (int c = 0; c < nchunk; ++c) {
        const int cur = c & 1;
        if (c + 1 < nchunk) {
            const int k0 = (c + 1) << 4;
            pa = *(const float4*)&A[(size_t)(bm + arow) * K + k0 + akq];
            pb = *(const float4*)&B[(size_t)(k0 + bkr) * N + bn + bnq];
        }
        #pragma unroll
        for (int kk = 0; kk < 16; ++kk) {
            const float4 a4 = *(const float4*)&As[cur][kk][ty << 2];
            const f32x2 b01 = *(const f32x2*)&Bs[cur][kk][tx << 2];
            const f32x2 b23 = *(const f32x2*)&Bs[cur][kk][(tx << 2) + 2];
            const float av[4] = {a4.x, a4.y, a4.z, a4.w};
            #pragma unroll
            for (int i = 0; i < 4; ++i) {
                const f32x2 aa = {av[i], av[i]};
                acc2[i][0] = __builtin_elementwise_fma(aa, b01, acc2[i][0]);
                acc2[i][1] = __builtin_elementwise_fma(aa, b23, acc2[i][1]);
            }
        }
        if (c + 1 < nchunk) {
            const int nxt = cur ^ 1;
            As[nxt][akq + 0][arow] = pa.x;
            As[nxt][akq + 1][arow] = pa.y;
            As[nxt][akq + 2][arow] = pa.z;
            As[nxt][akq + 3][arow] = pa.w;
            *(float4*)&Bs[nxt][bkr][bnq] = pb;
        }
        __syncthreads();
    }

    #pragma unroll
    for (int i = 0; i < 4; ++i) {
        const int row = bm + (ty << 2) + i;
        #pragma unroll
        for (int j = 0; j < 4; ++j) {
            const int col = bn + (tx << 2) + j;
            const float v = acc2[i][j >> 1][j & 1] + bias[col];
            if (is0) {
                const int n = row >> 11, l = row & 2047;
                const int f = col >> 5,  cc = col & 31;
                xq[((((size_t)n * FC + f) * LQ) + l) * CH + cc] = v;
            } else {
                const int n = row >> 11, s = row & 2047;
                const int f = col >> 6,  c64 = col & 63;
                float* dst = (c64 < CH) ? xk : xv;
                dst[((((size_t)n * FC + f) * SK) + s) * CH + (c64 & 31)] = v;
            }
        }
    }
}

// ------------------------------------------------------------------
// Combined: L2-normalize q rows (sign(alpha) folded) AND k rows, in
// place (arithmetic bit-identical to R2), emit bf16 hi copies, and
// zero-init maxhh_u/cnt (replaces in-graph memsets: ~43us each).
// ------------------------------------------------------------------
__global__ __launch_bounds__(256)
void norm_split_init_kernel(float* __restrict__ xq, unsigned short* __restrict__ qhi,
                            float* __restrict__ xk, unsigned short* __restrict__ khi,
                            const float* __restrict__ alpha,
                            unsigned int* __restrict__ maxhh_u, int* __restrict__ cnt)
{
    int r = blockIdx.x * blockDim.x + threadIdx.x;
    float* p;
    unsigned short* dhi;
    float sgn = 1.f;
    if (r < MHEAD * LQ) {
        maxhh_u[r] = 0u;      // ord_encode lower bound (0 < any encoded float)
        cnt[r] = 0;
        p   = xq + (size_t)r * CH;
        dhi = qhi + (size_t)r * CH;
        if (alpha[0] < 0.f) sgn = -1.f;
    } else {
        r -= MHEAD * LQ;
        p   = xk + (size_t)r * CH;
        dhi = khi + (size_t)r * CH;
    }

    float4 v[8];
    float ss = 0.f;
    #pragma unroll
    for (int i = 0; i < 8; ++i) {
        v[i] = *(const float4*)(p + i * 4);
        ss = fmaf(v[i].x, v[i].x, ss);
        ss = fmaf(v[i].y, v[i].y, ss);
        ss = fmaf(v[i].z, v[i].z, ss);
        ss = fmaf(v[i].w, v[i].w, ss);
    }
    const float inv = sgn / fmaxf(sqrtf(ss), 1e-12f);

    ushort8v hb[4];
    #pragma unroll
    for (int i = 0; i < 8; ++i) {
        float4 w;
        w.x = v[i].x * inv; w.y = v[i].y * inv;
        w.z = v[i].z * inv; w.w = v[i].w * inv;
        *(float4*)(p + i * 4) = w;
        hb[i >> 1][(i & 1) * 4 + 0] = f32_to_bf16_bits(w.x);
        hb[i >> 1][(i & 1) * 4 + 1] = f32_to_bf16_bits(w.y);
        hb[i >> 1][(i & 1) * 4 + 2] = f32_to_bf16_bits(w.z);
        hb[i >> 1][(i & 1) * 4 + 3] = f32_to_bf16_bits(w.w);
    }
    #pragma unroll
    for (int i = 0; i < 4; ++i)
        *(ushort8v*)(dhi + i * 8) = hb[i];
}

// ------------------------------------------------------------------
// Pass A1: bf16 MFMA scan, per-row hh max via ordered-uint atomicMax.
// Grid: 32 heads * 16 qb * 4 s-chunks = 2048 blocks, 4 waves.
// ------------------------------------------------------------------
__global__ __launch_bounds__(256, 4)
void maxpass_kernel(const unsigned short* __restrict__ qhi,
                    const unsigned short* __restrict__ khi,
                    unsigned int* __restrict__ maxhh_u)
{
    const int b    = blockIdx.x;
    const int sc   = b & 3;
    const int qb   = (b >> 2) & 15;
    const int h    = b >> 6;
    const int wave = threadIdx.x >> 6;
    const int lane = threadIdx.x & 63;
    const int qbase = qb * 128 + wave * 32;
    const int col   = lane & 31;
    const int g8    = (lane >> 5) * 8;

    const size_t qoff = ((size_t)h * LQ + qbase + col) * CH + g8;
    const bf16x8 ah0 = *(const bf16x8*)(qhi + qoff);
    const bf16x8 ah1 = *(const bf16x8*)(qhi + qoff + 16);

    const unsigned short* kh = khi + ((size_t)h * SK + sc * 512) * CH;
    const size_t koff = (size_t)col * CH + g8;

    float maxv[16];
    #pragma unroll
    for (int r = 0; r < 16; ++r) maxv[r] = -INFINITY;

    bf16x8 t0a = *(const bf16x8*)(kh + koff);
    bf16x8 t0b = *(const bf16x8*)(kh + koff + 16);
    bf16x8 t1a = *(const bf16x8*)(kh + koff + 32 * CH);
    bf16x8 t1b = *(const bf16x8*)(kh + koff + 32 * CH + 16);

    for (int sb = 0; sb < 16; sb += 2) {
        const bf16x8 c0a = t0a, c0b = t0b, c1a = t1a, c1b = t1b;
        if (sb + 2 < 16) {
            const size_t o = koff + (size_t)(sb + 2) * 32 * CH;
            t0a = *(const bf16x8*)(kh + o);
            t0b = *(const bf16x8*)(kh + o + 16);
            t1a = *(const bf16x8*)(kh + o + 32 * CH);
            t1b = *(const bf16x8*)(kh + o + 32 * CH + 16);
        }
        f32x16 c = {0.f, 0.f, 0.f, 0.f, 0.f, 0.f, 0.f, 0.f,
                    0.f, 0.f, 0.f, 0.f, 0.f, 0.f, 0.f, 0.f};
        c = MFMA32(ah0, c0a, c);
        c = MFMA32(ah1, c0b, c);
        #pragma unroll
        for (int r = 0; r < 16; ++r) maxv[r] = fmaxf(maxv[r], c[r]);
        f32x16 d = {0.f, 0.f, 0.f, 0.f, 0.f, 0.f, 0.f, 0.f,
                    0.f, 0.f, 0.f, 0.f, 0.f, 0.f, 0.f, 0.f};
        d = MFMA32(ah0, c1a, d);
        d = MFMA32(ah1, c1b, d);
        #pragma unroll
        for (int r = 0; r < 16; ++r) maxv[r] = fmaxf(maxv[r], d[r]);
    }

    #pragma unroll
    for (int r = 0; r < 16; ++r) {
        float v = maxv[r];
        #pragma unroll
        for (int m = 16; m >= 1; m >>= 1)
            v = fmaxf(v, __shfl_xor(v, m, 64));
        maxv[r] = v;
    }
    if (col == 0) {
        const int rbase = h * LQ + qbase + 4 * (lane >> 5);
        #pragma unroll
        for (int r = 0; r < 16; ++r)
            atomicMax(&maxhh_u[rbase + (r & 3) + 8 * (r >> 2)], ord_encode(maxv[r]));
    }
}

// ------------------------------------------------------------------
// Pass A2: identical MFMA scan; append s with hh >= max-MARGIN.
// ------------------------------------------------------------------
__global__ __launch_bounds__(256, 4)
void candpass_kernel(const unsigned short* __restrict__ qhi,
                     const unsigned short* __restrict__ khi,
                     const unsigned int* __restrict__ maxhh_u,
                     int* __restrict__ cnt, int* __restrict__ cand)
{
    const int b    = blockIdx.x;
    const int sc   = b & 3;
    const int qb   = (b >> 2) & 15;
    const int h    = b >> 6;
    const int wave = threadIdx.x >> 6;
    const int lane = threadIdx.x & 63;
    const int qbase = qb * 128 + wave * 32;
    const int col   = lane & 31;
    const int g8    = (lane >> 5) * 8;

    const size_t qoff = ((size_t)h * LQ + qbase + col) * CH + g8;
    const bf16x8 ah0 = *(const bf16x8*)(qhi + qoff);
    const bf16x8 ah1 = *(const bf16x8*)(qhi + qoff + 16);

    int   rows[16];
    float thr[16];
    {
        const int rbase = h * LQ + qbase + 4 * (lane >> 5);
        #pragma unroll
        for (int r = 0; r < 16; ++r) {
            rows[r] = rbase + (r & 3) + 8 * (r >> 2);
            thr[r]  = ord_decode(maxhh_u[rows[r]]) - MARGIN;
        }
    }

    const unsigned short* kh = khi + ((size_t)h * SK + sc * 512) * CH;
    const size_t koff = (size_t)col * CH + g8;
    const int sbase = sc * 512;

    bf16x8 t0a = *(const bf16x8*)(kh + koff);
    bf16x8 t0b = *(const bf16x8*)(kh + koff + 16);
    bf16x8 t1a = *(const bf16x8*)(kh + koff + 32 * CH);
    bf16x8 t1b = *(const bf16x8*)(kh + koff + 32 * CH + 16);

    for (int sb = 0; sb < 16; sb += 2) {
        const bf16x8 c0a = t0a, c0b = t0b, c1a = t1a, c1b = t1b;
        if (sb + 2 < 16) {
            const size_t o = koff + (size_t)(sb + 2) * 32 * CH;
            t0a = *(const bf16x8*)(kh + o);
            t0b = *(const bf16x8*)(kh + o + 16);
            t1a = *(const bf16x8*)(kh + o + 32 * CH);
            t1b = *(const bf16x8*)(kh + o + 32 * CH + 16);
        }
        f32x16 c = {0.f, 0.f, 0.f, 0.f, 0.f, 0.f, 0.f, 0.f,
                    0.f, 0.f, 0.f, 0.f, 0.f, 0.f, 0.f, 0.f};
        c = MFMA32(ah0, c0a, c);
        c = MFMA32(ah1, c0b, c);
        f32x16 d = {0.f, 0.f, 0.f, 0.f, 0.f, 0.f, 0.f, 0.f,
                    0.f, 0.f, 0.f, 0.f, 0.f, 0.f, 0.f, 0.f};
        d = MFMA32(ah0, c1a, d);
        d = MFMA32(ah1, c1b, d);
        const int s0 = sbase + sb * 32 + col;
        #pragma unroll
        for (int r = 0; r < 16; ++r) {
            if (c[r] >= thr[r]) {
                const int slot = atomicAdd(&cnt[rows[r]], 1);
                if (slot < CAP) cand[(size_t)rows[r] * CAP + slot] = s0;
            }
            if (d[r] >= thr[r]) {
                const int slot = atomicAdd(&cnt[rows[r]], 1);
                if (slot < CAP) cand[(size_t)rows[r] * CAP + slot] = s0 + 32;
            }
        }
    }
}

// ------------------------------------------------------------------
// Pass B: exact f32 refine (chain bit-identical to R2) + sigmoid +
// gather + scale; writes new_x0 as bf16 for the MFMA output GEMM.
// ------------------------------------------------------------------
__global__ __launch_bounds__(256)
void refine_gather_kernel(const float* __restrict__ qn,
                          const float* __restrict__ kn,
                          const int* __restrict__ cnt, const int* __restrict__ cand,
                          const float* __restrict__ xv,
                          const float* __restrict__ alpha, const float* __restrict__ beta,
                          unsigned short* __restrict__ nxb)  // (4,2048,256) bf16
{
    const int r = blockIdx.x * blockDim.x + threadIdx.x;  // h*2048 + l
    const int h = r >> 11, l = r & 2047;

    float qr[CH];
    #pragma unroll
    for (int i = 0; i < 8; ++i) {
        const float4 v = *(const float4*)(qn + (size_t)r * CH + i * 4);
        qr[i * 4 + 0] = v.x; qr[i * 4 + 1] = v.y;
        qr[i * 4 + 2] = v.z; qr[i * 4 + 3] = v.w;
    }

    int m = cnt[r];
    if (m > CAP) m = CAP;
    float best = -INFINITY;
    int   bidx = 0x7fffffff;
    for (int j = 0; j < m; ++j) {
        const int s = cand[(size_t)r * CAP + j];
        const float4* k4 = (const float4*)(kn + ((size_t)h * SK + s) * CH);
        float p = 0.f;
        #pragma unroll
        for (int c = 0; c < 8; ++c) {
            const float4 kv = k4[c];
            p = fmaf(qr[c * 4 + 0], kv.x, p);
            p = fmaf(qr[c * 4 + 1], kv.y, p);
            p = fmaf(qr[c * 4 + 2], kv.z, p);
            p = fmaf(qr[c * 4 + 3], kv.w, p);
        }
        if (p > best || (p == best && s < bidx)) { best = p; bidx = s; }
    }
    if (bidx == 0x7fffffff) bidx = 0;   // unreachable guard

    const float a = alpha[0], be = beta[0];
    float tv;
    int idx = bidx;
    if (a == 0.f) { idx = 0; tv = be; }
    else          { tv = fmaf(fabsf(a), best, be); }
    float val;
    if (tv >= 0.f) val = 1.f / (1.f + expf(-tv));
    else           { const float e = expf(tv); val = e / (1.f + e); }

    const float4* vr = (const float4*)(xv + ((size_t)h * SK + idx) * CH);
    const int n = h >> 3, f = h & 7;
    unsigned short* out = nxb + (((size_t)n * LQ + l) * (FC * CH)) + f * CH;
    #pragma unroll
    for (int i = 0; i < 8; ++i) {
        const float4 w = vr[i];
        ushort8v o;
        o[0] = f32_to_bf16_bits(w.x * val);
        o[1] = f32_to_bf16_bits(w.y * val);
        o[2] = f32_to_bf16_bits(w.z * val);
        o[3] = f32_to_bf16_bits(w.w * val);
        *(unsigned long long*)(out + i * 4) = __builtin_bit_cast(unsigned long long,
            *(const ulong1*)&o);
    }
}

// ------------------------------------------------------------------
// Wm (256x256 f32, row-major [k][n]) -> bf16 swizzled B-frag layout:
// wm_s[(k>>4)*4096 + n*16 + (k&15)]
// ------------------------------------------------------------------
__global__ __launch_bounds__(256)
void wmprep_kernel(const float* __restrict__ Wm, unsigned short* __restrict__ wm_s)
{
    const int i = blockIdx.x * 256 + threadIdx.x;   // 0..65535
    const int k = i >> 8, n = i & 255;
    wm_s[(k >> 4) * 4096 + n * 16 + (k & 15)] = f32_to_bf16_bits(Wm[k * 256 + n]);
}

// ------------------------------------------------------------------
// K6: out = nx(bf16) @ Wm(bf16 swizzled) + bm, f32 out. MFMA 32x32 tiles.
// ------------------------------------------------------------------
__global__ __launch_bounds__(256)
void gemm_out_mfma_kernel(const unsigned short* __restrict__ nxb,
                          const unsigned short* __restrict__ wm_s,
                          const float* __restrict__ bm, float* __restrict__ out)
{
    const int wave = threadIdx.x >> 6;
    const int lane = threadIdx.x & 63;
    const int idx  = blockIdx.x * 4 + wave;
    const int mt   = idx >> 3;
    const int nt   = idx & 7;
    const int col  = lane & 31;
    const int g8   = (lane >> 5) * 8;

    const unsigned short* aptr = nxb + (size_t)(mt * 32 + col) * 256 + g8;
    const unsigned short* bptr = wm_s + nt * 32 * 16 + col * 16 + g8;

    f32x16 acc = {0.f, 0.f, 0.f, 0.f, 0.f, 0.f, 0.f, 0.f,
                  0.f, 0.f, 0.f, 0.f, 0.f, 0.f, 0.f, 0.f};
    #pragma unroll 4
    for (int kc = 0; kc < 16; ++kc) {
        const bf16x8 a = *(const bf16x8*)(aptr + kc * 16);
        const bf16x8 bfr = *(const bf16x8*)(bptr + (size_t)kc * 4096);
        acc = MFMA32(a, bfr, acc);
    }

    const int n0 = nt * 32;
    const float bias = bm[n0 + col];
    #pragma unroll
    for (int r = 0; r < 16; ++r) {
        const int row = mt * 32 + (r & 3) + 8 * (r >> 2) + 4 * (lane >> 5);
        out[(size_t)row * 256 + n0 + col] = acc[r] + bias;
    }
}

// ------------------------------------------------------------------
extern "C" void kernel_launch(void* const* d_in, const int* in_sizes, int n_in,
                              void* d_out, int out_size, void* d_ws, size_t ws_size,
                              hipStream_t stream)
{
    const float* x0 = (const float*)d_in[0];
    const float* x1 = (const float*)d_in[1];
    const float* W0 = (const float*)d_in[2];
    const float* b0 = (const float*)d_in[3];
    const float* W1 = (const float*)d_in[4];
    const float* b1 = (const float*)d_in[5];
    const float* Wm = (const float*)d_in[6];
    const float* bm = (const float*)d_in[7];
    const float* alpha = (const float*)d_in[8];
    const float* beta  = (const float*)d_in[9];
    float* out = (float*)d_out;

    char* ws = (char*)d_ws;
    const size_t MB = 1024ull * 1024ull;
    float* x0q = (float*)(ws + 0);          // (32,2048,32) f32, normalized in place
    float* x1k = (float*)(ws + 8 * MB);     // (32,2048,32) f32, normalized in place
    float* x1v = (float*)(ws + 16 * MB);    // (32,2048,32) f32 values
    unsigned short* qhi = (unsigned short*)(ws + 24 * MB);  // 4MB (dead after A2)
    unsigned short* khi = (unsigned short*)(ws + 28 * MB);  // 4MB
    unsigned int* maxhh_u = (unsigned int*)(ws + 32 * MB);            // 256KB
    int* cnt  = (int*)(ws + 32 * MB + 256 * 1024);                    // 256KB
    int* cand = (int*)(ws + 32 * MB + 512 * 1024);                    // 3MB
    unsigned short* wm_s = (unsigned short*)(ws + 32 * MB + 3584 * 1024); // 128KB
    unsigned short* nxb  = (unsigned short*)(ws + 24 * MB); // reuse qhi region

    const int Mrows = NB * LQ;   // 8192

    // K1+K2 merged: projections with pk-fma, 1536 blocks
    proj_gemm_kernel<<<dim3(12, Mrows / 64), 256, 0, stream>>>(
        x0, x1, W0, b0, W1, b1, x0q, x1k, x1v);
    // Wm bf16 swizzle (independent)
    wmprep_kernel<<<256, 256, 0, stream>>>(Wm, wm_s);
    // K3: normalize q+k in place + bf16 hi copies + zero-init maxhh/cnt
    norm_split_init_kernel<<<(2 * MHEAD * LQ) / 256, 256, 0, stream>>>(
        x0q, qhi, x1k, khi, alpha, maxhh_u, cnt);
    // A1: MFMA hh max per row (s-split x4, atomicMax merge)
    maxpass_kernel<<<2048, 256, 0, stream>>>(qhi, khi, maxhh_u);
    // A2: MFMA hh candidate collection (s-split x4)
    candpass_kernel<<<2048, 256, 0, stream>>>(qhi, khi, maxhh_u, cnt, cand);
    // B: exact refine + sigmoid + gather + scale -> bf16 nx
    refine_gather_kernel<<<(MHEAD * LQ) / 256, 256, 0, stream>>>(
        x0q, x1k, cnt, cand, x1v, alpha, beta, nxb);
    // K6: out = nx @ Wm + bm via bf16 MFMA
    gemm_out_mfma_kernel<<<512, 256, 0, stream>>>(nxb, wm_s, bm, out);
}